// Round 1
// baseline (111.179 us; speedup 1.0000x reference)
//
#include <hip/hip_runtime.h>
#include <math.h>

static constexpr float kEps = 1e-5f;

// Fused: locally-connected conv (per-position weights) -> relu -> layernorm
// over the whole (OUT,OUT) map -> optional 2x2 maxpool. One block per sample;
// conv output staged in LDS.
template<int IN, int OUT, int K, int STRIDE, bool POOL, int BLK>
__global__ __launch_bounds__(BLK)
void lc_ln(const float* __restrict__ x, const float* __restrict__ wgt,
           const float* __restrict__ bias, const float* __restrict__ gam,
           const float* __restrict__ bet, float* __restrict__ out)
{
    constexpr int N = OUT * OUT;
    constexpr int NWAVE = BLK / 64;
    __shared__ float y[N];
    __shared__ float rsum[NWAVE], rsq[NWAVE];
    __shared__ float s_stats[2];

    const int b = blockIdx.x;
    const float* __restrict__ xb = x + (size_t)b * IN * IN;
    const int t = threadIdx.x;

    float lsum = 0.f, lsq = 0.f;
    for (int idx = t; idx < N; idx += BLK) {
        const int oh = idx / OUT;
        const int ow = idx - oh * OUT;
        const float* __restrict__ xp = xb + oh * STRIDE * IN + ow * STRIDE;
        const float* __restrict__ wp = wgt + (size_t)idx * (K * K);
        float acc = bias[idx];
        #pragma unroll
        for (int kh = 0; kh < K; ++kh) {
            #pragma unroll
            for (int kw = 0; kw < K; ++kw)
                acc = fmaf(xp[kh * IN + kw], wp[kh * K + kw], acc);
        }
        const float v = fmaxf(acc, 0.f);
        y[idx] = v;
        lsum += v;
        lsq = fmaf(v, v, lsq);
    }
    // wave reduce (width 64), then cross-wave via LDS
    #pragma unroll
    for (int off = 32; off > 0; off >>= 1) {
        lsum += __shfl_down(lsum, off, 64);
        lsq  += __shfl_down(lsq,  off, 64);
    }
    if ((t & 63) == 0) { rsum[t >> 6] = lsum; rsq[t >> 6] = lsq; }
    __syncthreads();   // also makes all y[] writes visible
    if (t == 0) {
        float s = 0.f, q = 0.f;
        #pragma unroll
        for (int i = 0; i < NWAVE; ++i) { s += rsum[i]; q += rsq[i]; }
        const float mean = s / (float)N;
        const float var  = q / (float)N - mean * mean;
        s_stats[0] = mean;
        s_stats[1] = rsqrtf(var + kEps);
    }
    __syncthreads();
    const float mean = s_stats[0], rs = s_stats[1];

    if (POOL) {
        constexpr int PO = OUT / 2;   // VALID pool drops odd tail row/col
        float* __restrict__ ob = out + (size_t)b * (PO * PO);
        for (int idx = t; idx < PO * PO; idx += BLK) {
            const int ph = idx / PO;
            const int pw = idx - ph * PO;
            const int base = (2 * ph) * OUT + 2 * pw;
            const float v0 = (y[base]        - mean) * rs * gam[base]        + bet[base];
            const float v1 = (y[base+1]      - mean) * rs * gam[base+1]      + bet[base+1];
            const float v2 = (y[base+OUT]    - mean) * rs * gam[base+OUT]    + bet[base+OUT];
            const float v3 = (y[base+OUT+1]  - mean) * rs * gam[base+OUT+1]  + bet[base+OUT+1];
            ob[idx] = fmaxf(fmaxf(v0, v1), fmaxf(v2, v3));
        }
    } else {
        float* __restrict__ ob = out + (size_t)b * N;
        for (int idx = t; idx < N; idx += BLK)
            ob[idx] = (y[idx] - mean) * rs * gam[idx] + bet[idx];
    }
}

// Fused FC (64 -> 1000) + softmax, one block per sample.
__global__ __launch_bounds__(256)
void fc_softmax(const float* __restrict__ h, const float* __restrict__ fcw,
                const float* __restrict__ fcb, float* __restrict__ out)
{
    __shared__ float hin[64];
    __shared__ float logits[1000];
    __shared__ float red[4];
    const int b = blockIdx.x, t = threadIdx.x;
    if (t < 64) hin[t] = h[b * 64 + t];
    __syncthreads();
    for (int j = t; j < 1000; j += 256) {
        const float* __restrict__ wr = fcw + j * 64;
        float acc = fcb[j];
        #pragma unroll
        for (int k = 0; k < 64; ++k) acc = fmaf(hin[k], wr[k], acc);
        logits[j] = acc;
    }
    __syncthreads();
    float lmax = -INFINITY;
    for (int j = t; j < 1000; j += 256) lmax = fmaxf(lmax, logits[j]);
    #pragma unroll
    for (int off = 32; off > 0; off >>= 1) lmax = fmaxf(lmax, __shfl_down(lmax, off, 64));
    if ((t & 63) == 0) red[t >> 6] = lmax;
    __syncthreads();
    const float gmax = fmaxf(fmaxf(red[0], red[1]), fmaxf(red[2], red[3]));
    __syncthreads();   // before red reuse
    float lsum = 0.f;
    for (int j = t; j < 1000; j += 256) {
        const float e = expf(logits[j] - gmax);
        logits[j] = e;
        lsum += e;
    }
    #pragma unroll
    for (int off = 32; off > 0; off >>= 1) lsum += __shfl_down(lsum, off, 64);
    if ((t & 63) == 0) red[t >> 6] = lsum;
    __syncthreads();
    const float inv = 1.f / (red[0] + red[1] + red[2] + red[3]);
    for (int j = t; j < 1000; j += 256) out[(size_t)b * 1000 + j] = logits[j] * inv;
}

extern "C" void kernel_launch(void* const* d_in, const int* in_sizes, int n_in,
                              void* d_out, int out_size, void* d_ws, size_t ws_size,
                              hipStream_t stream) {
    const float* x   = (const float*)d_in[0];
    const float* w1  = (const float*)d_in[1];
    const float* b1  = (const float*)d_in[2];
    const float* g1  = (const float*)d_in[3];
    const float* be1 = (const float*)d_in[4];
    const float* w2  = (const float*)d_in[5];
    const float* b2  = (const float*)d_in[6];
    const float* g2  = (const float*)d_in[7];
    const float* be2 = (const float*)d_in[8];
    const float* w3  = (const float*)d_in[9];
    const float* b3  = (const float*)d_in[10];
    const float* g3  = (const float*)d_in[11];
    const float* be3 = (const float*)d_in[12];
    const float* w4  = (const float*)d_in[13];
    const float* b4  = (const float*)d_in[14];
    const float* g4  = (const float*)d_in[15];
    const float* be4 = (const float*)d_in[16];
    const float* w5  = (const float*)d_in[17];
    const float* b5  = (const float*)d_in[18];
    const float* g5  = (const float*)d_in[19];
    const float* be5 = (const float*)d_in[20];
    const float* w6  = (const float*)d_in[21];
    const float* b6  = (const float*)d_in[22];
    const float* g6  = (const float*)d_in[23];
    const float* be6 = (const float*)d_in[24];
    const float* fcw = (const float*)d_in[25];
    const float* fcb = (const float*)d_in[26];

    float* buf0 = (float*)d_ws;                  // max 128*54*54 = 373248 floats
    float* buf1 = buf0 + (size_t)128 * 54 * 54;  // max 128*50*50 = 320000 floats

    const int B = 128;
    // L1: 224 -> conv(7, s2) -> 109 -> LN -> pool -> 54
    lc_ln<224, 109, 7, 2, true, 512><<<B, 512, 0, stream>>>(x,    w1, b1, g1, be1, buf0);
    // L2: 54 -> conv(5) -> 50 -> LN
    lc_ln<54,  50,  5, 1, false, 256><<<B, 256, 0, stream>>>(buf0, w2, b2, g2, be2, buf1);
    // L3: 50 -> conv(3) -> 48 -> LN -> pool -> 24
    lc_ln<50,  48,  3, 1, true, 256><<<B, 256, 0, stream>>>(buf1, w3, b3, g3, be3, buf0);
    // L4: 24 -> conv(3) -> 22 -> LN
    lc_ln<24,  22,  3, 1, false, 256><<<B, 256, 0, stream>>>(buf0, w4, b4, g4, be4, buf1);
    // L5: 22 -> conv(3) -> 20 -> LN -> pool -> 10
    lc_ln<22,  20,  3, 1, true, 256><<<B, 256, 0, stream>>>(buf1, w5, b5, g5, be5, buf0);
    // L6: 10 -> conv(3) -> 8 -> LN
    lc_ln<10,  8,   3, 1, false, 64><<<B, 64, 0, stream>>>(buf0, w6, b6, g6, be6, buf1);
    // FC + softmax
    fc_softmax<<<B, 256, 0, stream>>>(buf1, fcw, fcb, (float*)d_out);
}

// Round 2
// 88.643 us; speedup vs baseline: 1.2542x; 1.2542x over previous
//
#include <hip/hip_runtime.h>
#include <math.h>

static constexpr float kEps = 1e-5f;

// ---------------- weight transpose: wt[kk*N + idx] = w[idx*KK + kk] ----------------
__device__ inline void tpose(const float* __restrict__ w, float* __restrict__ wt,
                             int N, int KK, int tid, int nthreads) {
    for (int i = tid; i < N * KK; i += nthreads) {
        const int kk = i / N, idx = i - kk * N;
        wt[i] = w[idx * KK + kk];
    }
}

__global__ __launch_bounds__(256)
void transpose_weights(const float* __restrict__ w1, const float* __restrict__ w2,
                       const float* __restrict__ w3, const float* __restrict__ w4,
                       const float* __restrict__ w5, const float* __restrict__ w6,
                       float* __restrict__ t1, float* __restrict__ t2,
                       float* __restrict__ t3, float* __restrict__ t4,
                       float* __restrict__ t5, float* __restrict__ t6)
{
    const int tid = blockIdx.x * blockDim.x + threadIdx.x;
    const int nt  = gridDim.x * blockDim.x;
    tpose(w1, t1, 109 * 109, 49, tid, nt);
    tpose(w2, t2, 50 * 50,   25, tid, nt);
    tpose(w3, t3, 48 * 48,    9, tid, nt);
    tpose(w4, t4, 22 * 22,    9, tid, nt);
    tpose(w5, t5, 20 * 20,    9, tid, nt);
    tpose(w6, t6, 8 * 8,      9, tid, nt);
}

// ---------------- L1: stripe-parallel conv+relu with partial LN sums ----------------
template<int IN, int OUT, int K, int STRIDE, int RPS, int BLK>
__global__ __launch_bounds__(BLK)
void lc_conv_stripe(const float* __restrict__ x, const float* __restrict__ wt,
                    const float* __restrict__ bias, float* __restrict__ y,
                    float* __restrict__ partial, int nstripes)
{
    constexpr int N = OUT * OUT;
    constexpr int MAXROWS = RPS * STRIDE + K - STRIDE;
    constexpr int NWAVE = BLK / 64;
    __shared__ float xs[MAXROWS * IN];
    __shared__ float rsum[NWAVE], rsq[NWAVE];

    const int b = blockIdx.y, s = blockIdx.x, t = threadIdx.x;
    const int oh0 = s * RPS;
    const int oh1 = (OUT < oh0 + RPS) ? OUT : (oh0 + RPS);
    const int ih0 = oh0 * STRIDE;
    const int ih1 = (oh1 - 1) * STRIDE + K;
    const int nrows = ih1 - ih0;

    const float* __restrict__ xb = x + (size_t)b * IN * IN;
    for (int i = t; i < nrows * IN; i += BLK) xs[i] = xb[ih0 * IN + i];
    __syncthreads();

    float lsum = 0.f, lsq = 0.f;
    const int i0 = oh0 * OUT, i1 = oh1 * OUT;
    for (int idx = i0 + t; idx < i1; idx += BLK) {
        const int oh = idx / OUT;
        const int ow = idx - oh * OUT;
        const float* __restrict__ xp = xs + (oh * STRIDE - ih0) * IN + ow * STRIDE;
        float acc = bias[idx];
        #pragma unroll
        for (int kh = 0; kh < K; ++kh) {
            #pragma unroll
            for (int kw = 0; kw < K; ++kw)
                acc = fmaf(xp[kh * IN + kw], wt[(kh * K + kw) * N + idx], acc);
        }
        const float v = fmaxf(acc, 0.f);
        y[(size_t)b * N + idx] = v;
        lsum += v;
        lsq = fmaf(v, v, lsq);
    }
    #pragma unroll
    for (int off = 32; off > 0; off >>= 1) {
        lsum += __shfl_down(lsum, off, 64);
        lsq  += __shfl_down(lsq,  off, 64);
    }
    if ((t & 63) == 0) { rsum[t >> 6] = lsum; rsq[t >> 6] = lsq; }
    __syncthreads();
    if (t == 0) {
        float ss = 0.f, qq = 0.f;
        #pragma unroll
        for (int i = 0; i < NWAVE; ++i) { ss += rsum[i]; qq += rsq[i]; }
        partial[(b * nstripes + s) * 2]     = ss;
        partial[(b * nstripes + s) * 2 + 1] = qq;
    }
}

// ---------------- LN (+pool) over a precomputed conv map in global ----------------
template<int OUT, bool POOL, int BLK>
__global__ __launch_bounds__(BLK)
void ln_pool(const float* __restrict__ y, const float* __restrict__ partial,
             const float* __restrict__ gam, const float* __restrict__ bet,
             float* __restrict__ out, int nstripes)
{
    constexpr int N = OUT * OUT;
    __shared__ float s_stats[2];
    const int b = blockIdx.x, t = threadIdx.x;
    if (t == 0) {
        float ss = 0.f, qq = 0.f;
        for (int i = 0; i < nstripes; ++i) {
            ss += partial[(b * nstripes + i) * 2];
            qq += partial[(b * nstripes + i) * 2 + 1];
        }
        const float mean = ss / (float)N;
        const float var  = qq / (float)N - mean * mean;
        s_stats[0] = mean;
        s_stats[1] = rsqrtf(var + kEps);
    }
    __syncthreads();
    const float mean = s_stats[0], rs = s_stats[1];
    const float* __restrict__ yb = y + (size_t)b * N;

    if (POOL) {
        constexpr int PO = OUT / 2;
        float* __restrict__ ob = out + (size_t)b * (PO * PO);
        for (int idx = t; idx < PO * PO; idx += BLK) {
            const int ph = idx / PO;
            const int pw = idx - ph * PO;
            const int base = (2 * ph) * OUT + 2 * pw;
            const float v0 = (yb[base]         - mean) * rs * gam[base]         + bet[base];
            const float v1 = (yb[base + 1]     - mean) * rs * gam[base + 1]     + bet[base + 1];
            const float v2 = (yb[base + OUT]   - mean) * rs * gam[base + OUT]   + bet[base + OUT];
            const float v3 = (yb[base + OUT+1] - mean) * rs * gam[base + OUT+1] + bet[base + OUT+1];
            ob[idx] = fmaxf(fmaxf(v0, v1), fmaxf(v2, v3));
        }
    } else {
        float* __restrict__ ob = out + (size_t)b * N;
        for (int idx = t; idx < N; idx += BLK)
            ob[idx] = (yb[idx] - mean) * rs * gam[idx] + bet[idx];
    }
}

// ---------------- fused conv->relu->LN(->pool), input staged in LDS ----------------
template<int IN, int OUT, int K, int STRIDE, bool POOL, int BLK>
__global__ __launch_bounds__(BLK)
void lc_ln(const float* __restrict__ x, const float* __restrict__ wt,
           const float* __restrict__ bias, const float* __restrict__ gam,
           const float* __restrict__ bet, float* __restrict__ out)
{
    constexpr int N = OUT * OUT;
    constexpr int NWAVE = BLK / 64;
    __shared__ float xs[IN * IN];
    __shared__ float y[N];
    __shared__ float rsum[NWAVE], rsq[NWAVE];
    __shared__ float s_stats[2];

    const int b = blockIdx.x, t = threadIdx.x;
    const float* __restrict__ xb = x + (size_t)b * IN * IN;
    for (int i = t; i < IN * IN; i += BLK) xs[i] = xb[i];
    __syncthreads();

    float lsum = 0.f, lsq = 0.f;
    for (int idx = t; idx < N; idx += BLK) {
        const int oh = idx / OUT;
        const int ow = idx - oh * OUT;
        const float* __restrict__ xp = xs + oh * STRIDE * IN + ow * STRIDE;
        float acc = bias[idx];
        #pragma unroll
        for (int kh = 0; kh < K; ++kh) {
            #pragma unroll
            for (int kw = 0; kw < K; ++kw)
                acc = fmaf(xp[kh * IN + kw], wt[(kh * K + kw) * N + idx], acc);
        }
        const float v = fmaxf(acc, 0.f);
        y[idx] = v;
        lsum += v;
        lsq = fmaf(v, v, lsq);
    }
    #pragma unroll
    for (int off = 32; off > 0; off >>= 1) {
        lsum += __shfl_down(lsum, off, 64);
        lsq  += __shfl_down(lsq,  off, 64);
    }
    if ((t & 63) == 0) { rsum[t >> 6] = lsum; rsq[t >> 6] = lsq; }
    __syncthreads();
    if (t == 0) {
        float ss = 0.f, qq = 0.f;
        #pragma unroll
        for (int i = 0; i < NWAVE; ++i) { ss += rsum[i]; qq += rsq[i]; }
        const float mean = ss / (float)N;
        const float var  = qq / (float)N - mean * mean;
        s_stats[0] = mean;
        s_stats[1] = rsqrtf(var + kEps);
    }
    __syncthreads();
    const float mean = s_stats[0], rs = s_stats[1];

    if (POOL) {
        constexpr int PO = OUT / 2;
        float* __restrict__ ob = out + (size_t)b * (PO * PO);
        for (int idx = t; idx < PO * PO; idx += BLK) {
            const int ph = idx / PO;
            const int pw = idx - ph * PO;
            const int base = (2 * ph) * OUT + 2 * pw;
            const float v0 = (y[base]           - mean) * rs * gam[base]           + bet[base];
            const float v1 = (y[base + 1]       - mean) * rs * gam[base + 1]       + bet[base + 1];
            const float v2 = (y[base + OUT]     - mean) * rs * gam[base + OUT]     + bet[base + OUT];
            const float v3 = (y[base + OUT + 1] - mean) * rs * gam[base + OUT + 1] + bet[base + OUT + 1];
            ob[idx] = fmaxf(fmaxf(v0, v1), fmaxf(v2, v3));
        }
    } else {
        float* __restrict__ ob = out + (size_t)b * N;
        for (int idx = t; idx < N; idx += BLK)
            ob[idx] = (y[idx] - mean) * rs * gam[idx] + bet[idx];
    }
}

// ---------------- FC (64 -> 1000) + softmax ----------------
__global__ __launch_bounds__(256)
void fc_softmax(const float* __restrict__ h, const float* __restrict__ fcw,
                const float* __restrict__ fcb, float* __restrict__ out)
{
    __shared__ float hin[64];
    __shared__ float logits[1000];
    __shared__ float red[4];
    const int b = blockIdx.x, t = threadIdx.x;
    if (t < 64) hin[t] = h[b * 64 + t];
    __syncthreads();
    for (int j = t; j < 1000; j += 256) {
        const float* __restrict__ wr = fcw + j * 64;
        float acc = fcb[j];
        #pragma unroll
        for (int k = 0; k < 64; ++k) acc = fmaf(hin[k], wr[k], acc);
        logits[j] = acc;
    }
    __syncthreads();
    float lmax = -INFINITY;
    for (int j = t; j < 1000; j += 256) lmax = fmaxf(lmax, logits[j]);
    #pragma unroll
    for (int off = 32; off > 0; off >>= 1) lmax = fmaxf(lmax, __shfl_down(lmax, off, 64));
    if ((t & 63) == 0) red[t >> 6] = lmax;
    __syncthreads();
    const float gmax = fmaxf(fmaxf(red[0], red[1]), fmaxf(red[2], red[3]));
    __syncthreads();
    float lsum = 0.f;
    for (int j = t; j < 1000; j += 256) {
        const float e = expf(logits[j] - gmax);
        logits[j] = e;
        lsum += e;
    }
    #pragma unroll
    for (int off = 32; off > 0; off >>= 1) lsum += __shfl_down(lsum, off, 64);
    if ((t & 63) == 0) red[t >> 6] = lsum;
    __syncthreads();
    const float inv = 1.f / (red[0] + red[1] + red[2] + red[3]);
    for (int j = t; j < 1000; j += 256) out[(size_t)b * 1000 + j] = logits[j] * inv;
}

extern "C" void kernel_launch(void* const* d_in, const int* in_sizes, int n_in,
                              void* d_out, int out_size, void* d_ws, size_t ws_size,
                              hipStream_t stream) {
    const float* x   = (const float*)d_in[0];
    const float* w1  = (const float*)d_in[1];
    const float* b1  = (const float*)d_in[2];
    const float* g1  = (const float*)d_in[3];
    const float* be1 = (const float*)d_in[4];
    const float* w2  = (const float*)d_in[5];
    const float* b2  = (const float*)d_in[6];
    const float* g2  = (const float*)d_in[7];
    const float* be2 = (const float*)d_in[8];
    const float* w3  = (const float*)d_in[9];
    const float* b3  = (const float*)d_in[10];
    const float* g3  = (const float*)d_in[11];
    const float* be3 = (const float*)d_in[12];
    const float* w4  = (const float*)d_in[13];
    const float* b4  = (const float*)d_in[14];
    const float* g4  = (const float*)d_in[15];
    const float* be4 = (const float*)d_in[16];
    const float* w5  = (const float*)d_in[17];
    const float* b5  = (const float*)d_in[18];
    const float* g5  = (const float*)d_in[19];
    const float* be5 = (const float*)d_in[20];
    const float* w6  = (const float*)d_in[21];
    const float* b6  = (const float*)d_in[22];
    const float* g6  = (const float*)d_in[23];
    const float* be6 = (const float*)d_in[24];
    const float* fcw = (const float*)d_in[25];
    const float* fcb = (const float*)d_in[26];

    float* y1   = (float*)d_ws;            // 128*109*109 = 1,520,768
    float* buf0 = y1   + 1520768;          // 128*54*54   =   373,248
    float* buf1 = buf0 + 373248;           // 128*50*50   =   320,000
    float* w1t  = buf1 + 320000;           // 11881*49    =   582,169
    float* w2t  = w1t  + 582169;           // 2500*25     =    62,500
    float* w3t  = w2t  + 62500;            // 2304*9      =    20,736
    float* w4t  = w3t  + 20736;            // 484*9       =     4,356
    float* w5t  = w4t  + 4356;             // 400*9       =     3,600
    float* w6t  = w5t  + 3600;             // 64*9        =       576
    float* part = w6t  + 576;              // 128*8*2     =     2,048

    const int B = 128;

    transpose_weights<<<1024, 256, 0, stream>>>(w1, w2, w3, w4, w5, w6,
                                                w1t, w2t, w3t, w4t, w5t, w6t);

    // L1: 224 -> conv(7,s2) -> 109 (stripe-parallel) -> LN -> pool -> 54
    constexpr int RPS = 14, NSTRIPES = 8;   // ceil(109/14)=8
    lc_conv_stripe<224, 109, 7, 2, RPS, 256>
        <<<dim3(NSTRIPES, B), 256, 0, stream>>>(x, w1t, b1, y1, part, NSTRIPES);
    ln_pool<109, true, 256><<<B, 256, 0, stream>>>(y1, part, g1, be1, buf0, NSTRIPES);

    // L2: 54 -> conv(5) -> 50 -> LN
    lc_ln<54, 50, 5, 1, false, 256><<<B, 256, 0, stream>>>(buf0, w2t, b2, g2, be2, buf1);
    // L3: 50 -> conv(3) -> 48 -> LN -> pool -> 24
    lc_ln<50, 48, 3, 1, true, 256><<<B, 256, 0, stream>>>(buf1, w3t, b3, g3, be3, buf0);
    // L4: 24 -> conv(3) -> 22 -> LN
    lc_ln<24, 22, 3, 1, false, 256><<<B, 256, 0, stream>>>(buf0, w4t, b4, g4, be4, buf1);
    // L5: 22 -> conv(3) -> 20 -> LN -> pool -> 10
    lc_ln<22, 20, 3, 1, true, 256><<<B, 256, 0, stream>>>(buf1, w5t, b5, g5, be5, buf0);
    // L6: 10 -> conv(3) -> 8 -> LN
    lc_ln<10, 8, 3, 1, false, 64><<<B, 64, 0, stream>>>(buf0, w6t, b6, g6, be6, buf1);
    // FC + softmax
    fc_softmax<<<B, 256, 0, stream>>>(buf1, fcw, fcb, (float*)d_out);
}

// Round 3
// 55.089 us; speedup vs baseline: 2.0181x; 1.6091x over previous
//
#include <hip/hip_runtime.h>
#include <math.h>

static constexpr float kEps = 1e-5f;

// ---------- transpose weights into [kk][row][padded-col] layouts (pads = 0) ----------
__global__ __launch_bounds__(256)
void transpose_weights(const float* __restrict__ w1, const float* __restrict__ w2,
                       const float* __restrict__ w3, const float* __restrict__ w4,
                       const float* __restrict__ w5, const float* __restrict__ w6,
                       float* __restrict__ t1, float* __restrict__ t2,
                       float* __restrict__ t3, float* __restrict__ t4,
                       float* __restrict__ t5, float* __restrict__ t6)
{
    const int tid = blockIdx.x * blockDim.x + threadIdx.x;
    const int nt  = gridDim.x * blockDim.x;
    for (int i = tid; i < 49 * 109 * 112; i += nt) {            // w1t [49][109][112]
        const int kk = i / (109 * 112), r = i % (109 * 112);
        const int oh = r / 112, ow = r % 112;
        t1[i] = (ow < 109) ? w1[(oh * 109 + ow) * 49 + kk] : 0.f;
    }
    for (int i = tid; i < 25 * 50 * 52; i += nt) {              // w2t [25][50][52]
        const int kk = i / (50 * 52), r = i % (50 * 52);
        const int oh = r / 52, ow = r % 52;
        t2[i] = (ow < 50) ? w2[(oh * 50 + ow) * 25 + kk] : 0.f;
    }
    for (int i = tid; i < 9 * 2304; i += nt) {                  // w3t [9][2304]
        const int kk = i / 2304, idx = i % 2304;
        t3[i] = w3[idx * 9 + kk];
    }
    for (int i = tid; i < 9 * 22 * 24; i += nt) {               // w4t [9][22][24]
        const int kk = i / (22 * 24), r = i % (22 * 24);
        const int oh = r / 24, ow = r % 24;
        t4[i] = (ow < 22) ? w4[(oh * 22 + ow) * 9 + kk] : 0.f;
    }
    for (int i = tid; i < 9 * 400; i += nt) {                   // w5t [9][400]
        const int kk = i / 400, idx = i % 400;
        t5[i] = w5[idx * 9 + kk];
    }
    for (int i = tid; i < 9 * 64; i += nt) {                    // w6t [9][64]
        const int kk = i / 64, idx = i % 64;
        t6[i] = w6[idx * 9 + kk];
    }
}

// ---------- L1: 224 -> conv(7,s2) -> relu -> y[128][109][112] + partial LN sums ----------
// 2 samples per block (weight float4 loads shared), 1x4 output quad per thread.
__global__ __launch_bounds__(256)
void conv1(const float* __restrict__ x, const float* __restrict__ wt,
           const float* __restrict__ bias, float* __restrict__ y,
           float* __restrict__ partial)
{
    constexpr int IN = 224, OUT = 109, K = 7, RPS = 9, QPR = 28, NS = 13;
    __shared__ __align__(16) float xs0[23 * 224 + 8];
    __shared__ __align__(16) float xs1[23 * 224 + 8];
    __shared__ float red[4][4];

    const int s = blockIdx.x, bp = blockIdx.y, t = threadIdx.x;
    const int b0 = 2 * bp, b1 = b0 + 1;
    const int oh0 = s * RPS, ih0 = oh0 * 2;
    const int nrows = min(23, IN - ih0);
    {
        const float4* g0 = (const float4*)(x + ((size_t)b0 * IN + ih0) * IN);
        const float4* g1 = (const float4*)(x + ((size_t)b1 * IN + ih0) * IN);
        float4* s0 = (float4*)xs0;
        float4* s1 = (float4*)xs1;
        const int n4 = nrows * (IN / 4);
        for (int i = t; i < n4; i += 256) { s0[i] = g0[i]; s1[i] = g1[i]; }
    }
    __syncthreads();

    float lsum0 = 0.f, lsq0 = 0.f, lsum1 = 0.f, lsq1 = 0.f;
    if (t < RPS * QPR) {
        const int r = t / QPR, qc = t - r * QPR;
        const int oh = oh0 + r, ow0 = qc * 4;
        if (oh < OUT) {
            float acc0[4], acc1[4];
            #pragma unroll
            for (int o = 0; o < 4; ++o) {
                const float bv = (ow0 + o < OUT) ? bias[oh * OUT + ow0 + o] : 0.f;
                acc0[o] = bv; acc1[o] = bv;
            }
            const int lr0 = r * 2, c0 = ow0 * 2;
            #pragma unroll
            for (int kh = 0; kh < K; ++kh) {
                const float* p0 = xs0 + (lr0 + kh) * IN + c0;
                const float* p1 = xs1 + (lr0 + kh) * IN + c0;
                float a0[14], a1[14];
                #pragma unroll
                for (int i = 0; i < 7; ++i) {
                    const float2 v0 = *(const float2*)(p0 + 2 * i);
                    const float2 v1 = *(const float2*)(p1 + 2 * i);
                    a0[2 * i] = v0.x; a0[2 * i + 1] = v0.y;
                    a1[2 * i] = v1.x; a1[2 * i + 1] = v1.y;
                }
                #pragma unroll
                for (int kw = 0; kw < K; ++kw) {
                    const float4 w4 = *(const float4*)(wt + ((size_t)(kh * 7 + kw) * OUT + oh) * 112 + ow0);
                    acc0[0] = fmaf(a0[kw    ], w4.x, acc0[0]);  acc1[0] = fmaf(a1[kw    ], w4.x, acc1[0]);
                    acc0[1] = fmaf(a0[kw + 2], w4.y, acc0[1]);  acc1[1] = fmaf(a1[kw + 2], w4.y, acc1[1]);
                    acc0[2] = fmaf(a0[kw + 4], w4.z, acc0[2]);  acc1[2] = fmaf(a1[kw + 4], w4.z, acc1[2]);
                    acc0[3] = fmaf(a0[kw + 6], w4.w, acc0[3]);  acc1[3] = fmaf(a1[kw + 6], w4.w, acc1[3]);
                }
            }
            float4 st0, st1;
            #pragma unroll
            for (int o = 0; o < 4; ++o) {
                const float v0 = fmaxf(acc0[o], 0.f), v1 = fmaxf(acc1[o], 0.f);
                if (ow0 + o < OUT) {
                    lsum0 += v0; lsq0 = fmaf(v0, v0, lsq0);
                    lsum1 += v1; lsq1 = fmaf(v1, v1, lsq1);
                }
                (&st0.x)[o] = v0; (&st1.x)[o] = v1;
            }
            *(float4*)(y + ((size_t)b0 * OUT + oh) * 112 + ow0) = st0;
            *(float4*)(y + ((size_t)b1 * OUT + oh) * 112 + ow0) = st1;
        }
    }
    #pragma unroll
    for (int off = 32; off > 0; off >>= 1) {
        lsum0 += __shfl_down(lsum0, off, 64);  lsq0 += __shfl_down(lsq0, off, 64);
        lsum1 += __shfl_down(lsum1, off, 64);  lsq1 += __shfl_down(lsq1, off, 64);
    }
    if ((t & 63) == 0) {
        const int w = t >> 6;
        red[w][0] = lsum0; red[w][1] = lsq0; red[w][2] = lsum1; red[w][3] = lsq1;
    }
    __syncthreads();
    if (t == 0) {
        float a = 0, bq = 0, c = 0, d = 0;
        #pragma unroll
        for (int w = 0; w < 4; ++w) { a += red[w][0]; bq += red[w][1]; c += red[w][2]; d += red[w][3]; }
        partial[((size_t)b0 * NS + s) * 2]     = a;
        partial[((size_t)b0 * NS + s) * 2 + 1] = bq;
        partial[((size_t)b1 * NS + s) * 2]     = c;
        partial[((size_t)b1 * NS + s) * 2 + 1] = d;
    }
}

// ---------- block-wide mean/rsqrt(var) ----------
__device__ inline float2 block_stats(float lsum, float lsq, float invN,
                                     float (*red)[2], float* stat, int t)
{
    #pragma unroll
    for (int off = 32; off > 0; off >>= 1) {
        lsum += __shfl_down(lsum, off, 64);
        lsq  += __shfl_down(lsq,  off, 64);
    }
    if ((t & 63) == 0) { red[t >> 6][0] = lsum; red[t >> 6][1] = lsq; }
    __syncthreads();
    if (t == 0) {
        float s = 0, q = 0;
        #pragma unroll
        for (int w = 0; w < 4; ++w) { s += red[w][0]; q += red[w][1]; }
        const float m = s * invN;
        stat[0] = m;
        stat[1] = rsqrtf(q * invN - m * m + kEps);
    }
    __syncthreads();
    return make_float2(stat[0], stat[1]);
}

// ---------- everything after conv1, one block per sample ----------
__global__ __launch_bounds__(256)
void tail(const float* __restrict__ y1, const float* __restrict__ partial,
          const float* __restrict__ g1, const float* __restrict__ be1,
          const float* __restrict__ w2t, const float* __restrict__ b2,
          const float* __restrict__ g2, const float* __restrict__ be2,
          const float* __restrict__ w3t, const float* __restrict__ b3,
          const float* __restrict__ g3, const float* __restrict__ be3,
          const float* __restrict__ w4t, const float* __restrict__ b4,
          const float* __restrict__ g4, const float* __restrict__ be4,
          const float* __restrict__ w5t, const float* __restrict__ b5,
          const float* __restrict__ g5, const float* __restrict__ be5,
          const float* __restrict__ w6t, const float* __restrict__ b6,
          const float* __restrict__ g6, const float* __restrict__ be6,
          const float* __restrict__ fcw, const float* __restrict__ fcb,
          float* __restrict__ out)
{
    __shared__ __align__(16) float xs54[54 * 54 + 8];
    __shared__ __align__(16) float y50[50 * 52];
    __shared__ __align__(16) float y48[48 * 48];
    __shared__ __align__(16) float xs24[24 * 24 + 8];
    __shared__ __align__(16) float y22[22 * 24];
    __shared__ __align__(16) float y20[20 * 20];
    __shared__ __align__(16) float xs10[100];
    __shared__ float y8[64], h[64];
    __shared__ float logits[1000];
    __shared__ float red[4][2];
    __shared__ float stat[2];

    const int b = blockIdx.x, t = threadIdx.x;

    // ---- stats of layer-1 map from stripe partials ----
    if (t == 0) {
        float s = 0, q = 0;
        for (int i = 0; i < 13; ++i) {
            s += partial[((size_t)b * 13 + i) * 2];
            q += partial[((size_t)b * 13 + i) * 2 + 1];
        }
        const float m = s / 11881.f;
        stat[0] = m;
        stat[1] = rsqrtf(q / 11881.f - m * m + kEps);
    }
    __syncthreads();
    const float m1 = stat[0], r1 = stat[1];

    // ---- LN1 + 2x2 pool -> xs54 ----
    const float* yb = y1 + (size_t)b * 109 * 112;
    #pragma unroll
    for (int it = 0; it < 12; ++it) {
        const int idx = t + it * 256;
        if (idx < 54 * 54) {
            const int ph = idx / 54, pw = idx - ph * 54;
            const int r0 = 2 * ph, c0 = 2 * pw;
            const float2 u0 = *(const float2*)(yb + r0 * 112 + c0);
            const float2 u1 = *(const float2*)(yb + (r0 + 1) * 112 + c0);
            const int i00 = r0 * 109 + c0, i10 = i00 + 109;
            const float v0 = (u0.x - m1) * r1 * g1[i00]     + be1[i00];
            const float v1 = (u0.y - m1) * r1 * g1[i00 + 1] + be1[i00 + 1];
            const float v2 = (u1.x - m1) * r1 * g1[i10]     + be1[i10];
            const float v3 = (u1.y - m1) * r1 * g1[i10 + 1] + be1[i10 + 1];
            xs54[ph * 54 + pw] = fmaxf(fmaxf(v0, v1), fmaxf(v2, v3));
        }
    }
    __syncthreads();

    // ---- L2: 54 -> conv5 -> relu -> y50 ----
    float ls = 0.f, lq = 0.f;
    #pragma unroll
    for (int it = 0; it < 3; ++it) {
        const int task = t + it * 256;
        if (task < 650) {
            const int oh = task / 13, qc = task - oh * 13;
            const int ow0 = qc * 4;
            float acc[4];
            #pragma unroll
            for (int o = 0; o < 4; ++o) acc[o] = (ow0 + o < 50) ? b2[oh * 50 + ow0 + o] : 0.f;
            #pragma unroll
            for (int kh = 0; kh < 5; ++kh) {
                const float* xp = xs54 + (oh + kh) * 54 + ow0;
                float a[8];
                #pragma unroll
                for (int i = 0; i < 4; ++i) {
                    const float2 v = *(const float2*)(xp + 2 * i);
                    a[2 * i] = v.x; a[2 * i + 1] = v.y;
                }
                #pragma unroll
                for (int kw = 0; kw < 5; ++kw) {
                    const float4 w4 = *(const float4*)(w2t + ((size_t)(kh * 5 + kw) * 50 + oh) * 52 + ow0);
                    acc[0] = fmaf(a[kw    ], w4.x, acc[0]);
                    acc[1] = fmaf(a[kw + 1], w4.y, acc[1]);
                    acc[2] = fmaf(a[kw + 2], w4.z, acc[2]);
                    acc[3] = fmaf(a[kw + 3], w4.w, acc[3]);
                }
            }
            #pragma unroll
            for (int o = 0; o < 4; ++o) {
                const float v = fmaxf(acc[o], 0.f);
                y50[oh * 52 + ow0 + o] = v;
                if (ow0 + o < 50) { ls += v; lq = fmaf(v, v, lq); }
            }
        }
    }
    const float2 s2 = block_stats(ls, lq, 1.f / 2500.f, red, stat, t);

    // ---- LN2 in place ----
    #pragma unroll
    for (int it = 0; it < 10; ++it) {
        const int idx = t + it * 256;
        if (idx < 2500) {
            const int oh = idx / 50, ow = idx - oh * 50;
            const int p = oh * 52 + ow;
            y50[p] = (y50[p] - s2.x) * s2.y * g2[idx] + be2[idx];
        }
    }
    __syncthreads();

    // ---- L3: 50 -> conv3 -> relu -> y48 ----
    ls = 0.f; lq = 0.f;
    #pragma unroll
    for (int it = 0; it < 3; ++it) {
        const int task = t + it * 256;
        if (task < 576) {
            const int oh = task / 12, qc = task - oh * 12;
            const int ow0 = qc * 4;
            float acc[4];
            #pragma unroll
            for (int o = 0; o < 4; ++o) acc[o] = b3[oh * 48 + ow0 + o];
            #pragma unroll
            for (int kh = 0; kh < 3; ++kh) {
                const float* xp = y50 + (oh + kh) * 52 + ow0;
                float a[6];
                #pragma unroll
                for (int i = 0; i < 3; ++i) {
                    const float2 v = *(const float2*)(xp + 2 * i);
                    a[2 * i] = v.x; a[2 * i + 1] = v.y;
                }
                #pragma unroll
                for (int kw = 0; kw < 3; ++kw) {
                    const float4 w4 = *(const float4*)(w3t + (size_t)(kh * 3 + kw) * 2304 + oh * 48 + ow0);
                    acc[0] = fmaf(a[kw    ], w4.x, acc[0]);
                    acc[1] = fmaf(a[kw + 1], w4.y, acc[1]);
                    acc[2] = fmaf(a[kw + 2], w4.z, acc[2]);
                    acc[3] = fmaf(a[kw + 3], w4.w, acc[3]);
                }
            }
            float4 st;
            #pragma unroll
            for (int o = 0; o < 4; ++o) {
                const float v = fmaxf(acc[o], 0.f);
                (&st.x)[o] = v; ls += v; lq = fmaf(v, v, lq);
            }
            *(float4*)(y48 + oh * 48 + ow0) = st;
        }
    }
    const float2 s3 = block_stats(ls, lq, 1.f / 2304.f, red, stat, t);

    // ---- LN3 + pool -> xs24 ----
    #pragma unroll
    for (int it = 0; it < 3; ++it) {
        const int idx = t + it * 256;
        if (idx < 576) {
            const int ph = idx / 24, pw = idx - ph * 24;
            const int r0 = 2 * ph, c0 = 2 * pw;
            const float2 u0 = *(const float2*)(y48 + r0 * 48 + c0);
            const float2 u1 = *(const float2*)(y48 + (r0 + 1) * 48 + c0);
            const int i00 = r0 * 48 + c0, i10 = i00 + 48;
            const float v0 = (u0.x - s3.x) * s3.y * g3[i00]     + be3[i00];
            const float v1 = (u0.y - s3.x) * s3.y * g3[i00 + 1] + be3[i00 + 1];
            const float v2 = (u1.x - s3.x) * s3.y * g3[i10]     + be3[i10];
            const float v3 = (u1.y - s3.x) * s3.y * g3[i10 + 1] + be3[i10 + 1];
            xs24[ph * 24 + pw] = fmaxf(fmaxf(v0, v1), fmaxf(v2, v3));
        }
    }
    __syncthreads();

    // ---- L4: 24 -> conv3 -> relu -> y22 ----
    ls = 0.f; lq = 0.f;
    if (t < 132) {
        const int oh = t / 6, qc = t - oh * 6;
        const int ow0 = qc * 4;
        float acc[4];
        #pragma unroll
        for (int o = 0; o < 4; ++o) acc[o] = (ow0 + o < 22) ? b4[oh * 22 + ow0 + o] : 0.f;
        #pragma unroll
        for (int kh = 0; kh < 3; ++kh) {
            const float* xp = xs24 + (oh + kh) * 24 + ow0;
            float a[6];
            #pragma unroll
            for (int i = 0; i < 3; ++i) {
                const float2 v = *(const float2*)(xp + 2 * i);
                a[2 * i] = v.x; a[2 * i + 1] = v.y;
            }
            #pragma unroll
            for (int kw = 0; kw < 3; ++kw) {
                const float4 w4 = *(const float4*)(w4t + ((size_t)(kh * 3 + kw) * 22 + oh) * 24 + ow0);
                acc[0] = fmaf(a[kw    ], w4.x, acc[0]);
                acc[1] = fmaf(a[kw + 1], w4.y, acc[1]);
                acc[2] = fmaf(a[kw + 2], w4.z, acc[2]);
                acc[3] = fmaf(a[kw + 3], w4.w, acc[3]);
            }
        }
        #pragma unroll
        for (int o = 0; o < 4; ++o) {
            const float v = fmaxf(acc[o], 0.f);
            y22[oh * 24 + ow0 + o] = v;
            if (ow0 + o < 22) { ls += v; lq = fmaf(v, v, lq); }
        }
    }
    const float2 s4 = block_stats(ls, lq, 1.f / 484.f, red, stat, t);

    // ---- LN4 in place ----
    #pragma unroll
    for (int it = 0; it < 2; ++it) {
        const int idx = t + it * 256;
        if (idx < 484) {
            const int oh = idx / 22, ow = idx - oh * 22;
            const int p = oh * 24 + ow;
            y22[p] = (y22[p] - s4.x) * s4.y * g4[idx] + be4[idx];
        }
    }
    __syncthreads();

    // ---- L5: 22 -> conv3 -> relu -> y20 ----
    ls = 0.f; lq = 0.f;
    if (t < 100) {
        const int oh = t / 5, qc = t - oh * 5;
        const int ow0 = qc * 4;
        float acc[4];
        #pragma unroll
        for (int o = 0; o < 4; ++o) acc[o] = b5[oh * 20 + ow0 + o];
        #pragma unroll
        for (int kh = 0; kh < 3; ++kh) {
            const float* xp = y22 + (oh + kh) * 24 + ow0;
            float a[6];
            #pragma unroll
            for (int i = 0; i < 3; ++i) {
                const float2 v = *(const float2*)(xp + 2 * i);
                a[2 * i] = v.x; a[2 * i + 1] = v.y;
            }
            #pragma unroll
            for (int kw = 0; kw < 3; ++kw) {
                const float4 w4 = *(const float4*)(w5t + (size_t)(kh * 3 + kw) * 400 + oh * 20 + ow0);
                acc[0] = fmaf(a[kw    ], w4.x, acc[0]);
                acc[1] = fmaf(a[kw + 1], w4.y, acc[1]);
                acc[2] = fmaf(a[kw + 2], w4.z, acc[2]);
                acc[3] = fmaf(a[kw + 3], w4.w, acc[3]);
            }
        }
        #pragma unroll
        for (int o = 0; o < 4; ++o) {
            const float v = fmaxf(acc[o], 0.f);
            y20[oh * 20 + ow0 + o] = v;
            ls += v; lq = fmaf(v, v, lq);
        }
    }
    const float2 s5 = block_stats(ls, lq, 1.f / 400.f, red, stat, t);

    // ---- LN5 + pool -> xs10 ----
    if (t < 100) {
        const int ph = t / 10, pw = t - ph * 10;
        const int r0 = 2 * ph, c0 = 2 * pw;
        const float2 u0 = *(const float2*)(y20 + r0 * 20 + c0);
        const float2 u1 = *(const float2*)(y20 + (r0 + 1) * 20 + c0);
        const int i00 = r0 * 20 + c0, i10 = i00 + 20;
        const float v0 = (u0.x - s5.x) * s5.y * g5[i00]     + be5[i00];
        const float v1 = (u0.y - s5.x) * s5.y * g5[i00 + 1] + be5[i00 + 1];
        const float v2 = (u1.x - s5.x) * s5.y * g5[i10]     + be5[i10];
        const float v3 = (u1.y - s5.x) * s5.y * g5[i10 + 1] + be5[i10 + 1];
        xs10[ph * 10 + pw] = fmaxf(fmaxf(v0, v1), fmaxf(v2, v3));
    }
    __syncthreads();

    // ---- L6: 10 -> conv3 -> relu -> y8 ----
    ls = 0.f; lq = 0.f;
    if (t < 16) {
        const int oh = t / 2, qc = t - oh * 2;
        const int ow0 = qc * 4;
        float acc[4];
        #pragma unroll
        for (int o = 0; o < 4; ++o) acc[o] = b6[oh * 8 + ow0 + o];
        #pragma unroll
        for (int kh = 0; kh < 3; ++kh) {
            const float* xp = xs10 + (oh + kh) * 10 + ow0;
            float a[6];
            #pragma unroll
            for (int i = 0; i < 3; ++i) {
                const float2 v = *(const float2*)(xp + 2 * i);
                a[2 * i] = v.x; a[2 * i + 1] = v.y;
            }
            #pragma unroll
            for (int kw = 0; kw < 3; ++kw) {
                const float4 w4 = *(const float4*)(w6t + (size_t)(kh * 3 + kw) * 64 + oh * 8 + ow0);
                acc[0] = fmaf(a[kw    ], w4.x, acc[0]);
                acc[1] = fmaf(a[kw + 1], w4.y, acc[1]);
                acc[2] = fmaf(a[kw + 2], w4.z, acc[2]);
                acc[3] = fmaf(a[kw + 3], w4.w, acc[3]);
            }
        }
        #pragma unroll
        for (int o = 0; o < 4; ++o) {
            const float v = fmaxf(acc[o], 0.f);
            y8[oh * 8 + ow0 + o] = v;
            ls += v; lq = fmaf(v, v, lq);
        }
    }
    const float2 s6 = block_stats(ls, lq, 1.f / 64.f, red, stat, t);

    // ---- LN6 -> h ----
    if (t < 64) h[t] = (y8[t] - s6.x) * s6.y * g6[t] + be6[t];
    __syncthreads();

    // ---- FC 64 -> 1000 ----
    #pragma unroll
    for (int it = 0; it < 4; ++it) {
        const int j = t + it * 256;
        if (j < 1000) {
            const float4* wr = (const float4*)(fcw + (size_t)j * 64);
            float acc = fcb[j];
            #pragma unroll
            for (int k = 0; k < 16; ++k) {
                const float4 w4 = wr[k];
                acc = fmaf(h[4 * k], w4.x,
                      fmaf(h[4 * k + 1], w4.y,
                      fmaf(h[4 * k + 2], w4.z,
                      fmaf(h[4 * k + 3], w4.w, acc))));
            }
            logits[j] = acc;
        }
    }
    __syncthreads();

    // ---- softmax ----
    float lmax = -INFINITY;
    #pragma unroll
    for (int it = 0; it < 4; ++it) {
        const int j = t + it * 256;
        if (j < 1000) lmax = fmaxf(lmax, logits[j]);
    }
    #pragma unroll
    for (int off = 32; off > 0; off >>= 1) lmax = fmaxf(lmax, __shfl_down(lmax, off, 64));
    if ((t & 63) == 0) red[t >> 6][0] = lmax;
    __syncthreads();
    const float gmax = fmaxf(fmaxf(red[0][0], red[1][0]), fmaxf(red[2][0], red[3][0]));
    __syncthreads();
    float lsum = 0.f;
    #pragma unroll
    for (int it = 0; it < 4; ++it) {
        const int j = t + it * 256;
        if (j < 1000) {
            const float e = expf(logits[j] - gmax);
            logits[j] = e;
            lsum += e;
        }
    }
    #pragma unroll
    for (int off = 32; off > 0; off >>= 1) lsum += __shfl_down(lsum, off, 64);
    if ((t & 63) == 0) red[t >> 6][0] = lsum;
    __syncthreads();
    const float inv = 1.f / (red[0][0] + red[1][0] + red[2][0] + red[3][0]);
    #pragma unroll
    for (int it = 0; it < 4; ++it) {
        const int j = t + it * 256;
        if (j < 1000) out[(size_t)b * 1000 + j] = logits[j] * inv;
    }
}

extern "C" void kernel_launch(void* const* d_in, const int* in_sizes, int n_in,
                              void* d_out, int out_size, void* d_ws, size_t ws_size,
                              hipStream_t stream) {
    const float* x   = (const float*)d_in[0];
    const float* w1  = (const float*)d_in[1];
    const float* b1  = (const float*)d_in[2];
    const float* g1  = (const float*)d_in[3];
    const float* be1 = (const float*)d_in[4];
    const float* w2  = (const float*)d_in[5];
    const float* b2  = (const float*)d_in[6];
    const float* g2  = (const float*)d_in[7];
    const float* be2 = (const float*)d_in[8];
    const float* w3  = (const float*)d_in[9];
    const float* b3  = (const float*)d_in[10];
    const float* g3  = (const float*)d_in[11];
    const float* be3 = (const float*)d_in[12];
    const float* w4  = (const float*)d_in[13];
    const float* b4  = (const float*)d_in[14];
    const float* g4  = (const float*)d_in[15];
    const float* be4 = (const float*)d_in[16];
    const float* w5  = (const float*)d_in[17];
    const float* b5  = (const float*)d_in[18];
    const float* g5  = (const float*)d_in[19];
    const float* be5 = (const float*)d_in[20];
    const float* w6  = (const float*)d_in[21];
    const float* b6  = (const float*)d_in[22];
    const float* g6  = (const float*)d_in[23];
    const float* be6 = (const float*)d_in[24];
    const float* fcw = (const float*)d_in[25];
    const float* fcb = (const float*)d_in[26];

    float* y1p  = (float*)d_ws;                 // 128*109*112 = 1,562,624
    float* w1t  = y1p  + 1562624;               // 49*109*112  =   598,192
    float* w2t  = w1t  + 598192;                // 25*50*52    =    65,000
    float* w3t  = w2t  + 65000;                 // 9*2304      =    20,736
    float* w4t  = w3t  + 20736;                 // 9*22*24     =     4,752
    float* w5t  = w4t  + 4752;                  // 9*400       =     3,600
    float* w6t  = w5t  + 3600;                  // 9*64        =       576
    float* part = w6t  + 576;                   // 128*13*2    =     3,328

    transpose_weights<<<512, 256, 0, stream>>>(w1, w2, w3, w4, w5, w6,
                                               w1t, w2t, w3t, w4t, w5t, w6t);

    conv1<<<dim3(13, 64), 256, 0, stream>>>(x, w1t, b1, y1p, part);

    tail<<<128, 256, 0, stream>>>(y1p, part, g1, be1,
                                  w2t, b2, g2, be2,
                                  w3t, b3, g3, be3,
                                  w4t, b4, g4, be4,
                                  w5t, b5, g5, be5,
                                  w6t, b6, g6, be6,
                                  fcw, fcb, (float*)d_out);
}

// Round 4
// 54.663 us; speedup vs baseline: 2.0339x; 1.0078x over previous
//
#include <hip/hip_runtime.h>
#include <math.h>

static constexpr float kEps = 1e-5f;

// ---------- transpose weights into [kk][row][padded-col] layouts (pads = 0) ----------
__global__ __launch_bounds__(256)
void transpose_weights(const float* __restrict__ w1, const float* __restrict__ w2,
                       const float* __restrict__ w3, const float* __restrict__ w4,
                       const float* __restrict__ w5, const float* __restrict__ w6,
                       float* __restrict__ t1, float* __restrict__ t2,
                       float* __restrict__ t3, float* __restrict__ t4,
                       float* __restrict__ t5, float* __restrict__ t6)
{
    const int tid = blockIdx.x * blockDim.x + threadIdx.x;
    const int nt  = gridDim.x * blockDim.x;
    for (int i = tid; i < 49 * 109 * 112; i += nt) {            // w1t [49][109][112]
        const int kk = i / (109 * 112), r = i % (109 * 112);
        const int oh = r / 112, ow = r % 112;
        t1[i] = (ow < 109) ? w1[(oh * 109 + ow) * 49 + kk] : 0.f;
    }
    for (int i = tid; i < 25 * 50 * 52; i += nt) {              // w2t [25][50][52]
        const int kk = i / (50 * 52), r = i % (50 * 52);
        const int oh = r / 52, ow = r % 52;
        t2[i] = (ow < 50) ? w2[(oh * 50 + ow) * 25 + kk] : 0.f;
    }
    for (int i = tid; i < 9 * 2304; i += nt) {                  // w3t [9][2304]
        const int kk = i / 2304, idx = i % 2304;
        t3[i] = w3[idx * 9 + kk];
    }
    for (int i = tid; i < 9 * 22 * 24; i += nt) {               // w4t [9][22][24]
        const int kk = i / (22 * 24), r = i % (22 * 24);
        const int oh = r / 24, ow = r % 24;
        t4[i] = (ow < 22) ? w4[(oh * 22 + ow) * 9 + kk] : 0.f;
    }
    for (int i = tid; i < 9 * 400; i += nt) {                   // w5t [9][400]
        const int kk = i / 400, idx = i % 400;
        t5[i] = w5[idx * 9 + kk];
    }
    for (int i = tid; i < 9 * 64; i += nt) {                    // w6t [9][64]
        const int kk = i / 64, idx = i % 64;
        t6[i] = w6[idx * 9 + kk];
    }
}

// ---------- L1: 224 -> conv(7,s2) -> relu -> y[128][109][112] + partial LN sums ----------
// RPS=4 rows/stripe keeps LDS at 23.3 KB -> ~6 blocks/CU (12 waves) for latency hiding.
// 2 samples per block share every weight load; 1x4 output quad per thread.
__global__ __launch_bounds__(128)
void conv1(const float* __restrict__ x, const float* __restrict__ wt,
           const float* __restrict__ bias, float* __restrict__ y,
           float* __restrict__ partial)
{
    constexpr int IN = 224, OUT = 109, K = 7, RPS = 4, QPR = 28, NS = 28;
    constexpr int ROWS = (RPS - 1) * 2 + K;   // 13
    __shared__ __align__(16) float xs0[ROWS * IN];
    __shared__ __align__(16) float xs1[ROWS * IN];
    __shared__ float red[2][4];

    const int s = blockIdx.x, bp = blockIdx.y, t = threadIdx.x;
    const int b0 = 2 * bp, b1 = b0 + 1;
    const int oh0 = s * RPS, ih0 = oh0 * 2;
    const int nrows = min(ROWS, IN - ih0);
    {
        const float4* g0 = (const float4*)(x + ((size_t)b0 * IN + ih0) * IN);
        const float4* g1 = (const float4*)(x + ((size_t)b1 * IN + ih0) * IN);
        float4* s0 = (float4*)xs0;
        float4* s1 = (float4*)xs1;
        const int n4 = nrows * (IN / 4);
        for (int i = t; i < n4; i += 128) { s0[i] = g0[i]; s1[i] = g1[i]; }
    }
    __syncthreads();

    float lsum0 = 0.f, lsq0 = 0.f, lsum1 = 0.f, lsq1 = 0.f;
    if (t < RPS * QPR) {
        const int r = t / QPR, qc = t - r * QPR;
        const int oh = oh0 + r, ow0 = qc * 4;
        if (oh < OUT) {
            float acc0[4], acc1[4];
            #pragma unroll
            for (int o = 0; o < 4; ++o) {
                const float bv = (ow0 + o < OUT) ? bias[oh * OUT + ow0 + o] : 0.f;
                acc0[o] = bv; acc1[o] = bv;
            }
            const int lr0 = r * 2, c0 = ow0 * 2;
            #pragma unroll
            for (int kh = 0; kh < K; ++kh) {
                const float* p0 = xs0 + (lr0 + kh) * IN + c0;
                const float* p1 = xs1 + (lr0 + kh) * IN + c0;
                float a0[14], a1[14];
                #pragma unroll
                for (int i = 0; i < 7; ++i) {
                    const float2 v0 = *(const float2*)(p0 + 2 * i);
                    const float2 v1 = *(const float2*)(p1 + 2 * i);
                    a0[2 * i] = v0.x; a0[2 * i + 1] = v0.y;
                    a1[2 * i] = v1.x; a1[2 * i + 1] = v1.y;
                }
                #pragma unroll
                for (int kw = 0; kw < K; ++kw) {
                    const float4 w4 = *(const float4*)(wt + ((size_t)(kh * 7 + kw) * OUT + oh) * 112 + ow0);
                    acc0[0] = fmaf(a0[kw    ], w4.x, acc0[0]);  acc1[0] = fmaf(a1[kw    ], w4.x, acc1[0]);
                    acc0[1] = fmaf(a0[kw + 2], w4.y, acc0[1]);  acc1[1] = fmaf(a1[kw + 2], w4.y, acc1[1]);
                    acc0[2] = fmaf(a0[kw + 4], w4.z, acc0[2]);  acc1[2] = fmaf(a1[kw + 4], w4.z, acc1[2]);
                    acc0[3] = fmaf(a0[kw + 6], w4.w, acc0[3]);  acc1[3] = fmaf(a1[kw + 6], w4.w, acc1[3]);
                }
            }
            float4 st0, st1;
            #pragma unroll
            for (int o = 0; o < 4; ++o) {
                const float v0 = fmaxf(acc0[o], 0.f), v1 = fmaxf(acc1[o], 0.f);
                if (ow0 + o < OUT) {
                    lsum0 += v0; lsq0 = fmaf(v0, v0, lsq0);
                    lsum1 += v1; lsq1 = fmaf(v1, v1, lsq1);
                }
                (&st0.x)[o] = v0; (&st1.x)[o] = v1;
            }
            *(float4*)(y + ((size_t)b0 * OUT + oh) * 112 + ow0) = st0;
            *(float4*)(y + ((size_t)b1 * OUT + oh) * 112 + ow0) = st1;
        }
    }
    #pragma unroll
    for (int off = 32; off > 0; off >>= 1) {
        lsum0 += __shfl_down(lsum0, off, 64);  lsq0 += __shfl_down(lsq0, off, 64);
        lsum1 += __shfl_down(lsum1, off, 64);  lsq1 += __shfl_down(lsq1, off, 64);
    }
    if ((t & 63) == 0) {
        const int w = t >> 6;
        red[w][0] = lsum0; red[w][1] = lsq0; red[w][2] = lsum1; red[w][3] = lsq1;
    }
    __syncthreads();
    if (t == 0) {
        const float a = red[0][0] + red[1][0], bq = red[0][1] + red[1][1];
        const float c = red[0][2] + red[1][2], d  = red[0][3] + red[1][3];
        partial[((size_t)b0 * NS + s) * 2]     = a;
        partial[((size_t)b0 * NS + s) * 2 + 1] = bq;
        partial[((size_t)b1 * NS + s) * 2]     = c;
        partial[((size_t)b1 * NS + s) * 2 + 1] = d;
    }
}

// ---------- block-wide mean/rsqrt(var): ONE barrier, all threads compute ----------
__device__ inline float2 block_stats4(float lsum, float lsq, float invN,
                                      float (*red)[2], int t)
{
    #pragma unroll
    for (int off = 32; off > 0; off >>= 1) {
        lsum += __shfl_down(lsum, off, 64);
        lsq  += __shfl_down(lsq,  off, 64);
    }
    if ((t & 63) == 0) { red[t >> 6][0] = lsum; red[t >> 6][1] = lsq; }
    __syncthreads();
    const float s = red[0][0] + red[1][0] + red[2][0] + red[3][0];
    const float q = red[0][1] + red[1][1] + red[2][1] + red[3][1];
    const float m = s * invN;
    return make_float2(m, rsqrtf(q * invN - m * m + kEps));
}

// ---------- everything after conv1, one block per sample ----------
__global__ __launch_bounds__(256)
void tail(const float* __restrict__ y1, const float* __restrict__ partial,
          const float* __restrict__ g1, const float* __restrict__ be1,
          const float* __restrict__ w2t, const float* __restrict__ b2,
          const float* __restrict__ g2, const float* __restrict__ be2,
          const float* __restrict__ w3t, const float* __restrict__ b3,
          const float* __restrict__ g3, const float* __restrict__ be3,
          const float* __restrict__ w4t, const float* __restrict__ b4,
          const float* __restrict__ g4, const float* __restrict__ be4,
          const float* __restrict__ w5t, const float* __restrict__ b5,
          const float* __restrict__ g5, const float* __restrict__ be5,
          const float* __restrict__ w6t, const float* __restrict__ b6,
          const float* __restrict__ g6, const float* __restrict__ be6,
          const float* __restrict__ fcw, const float* __restrict__ fcb,
          float* __restrict__ out)
{
    constexpr int NS = 28;
    __shared__ __align__(16) float xs54[54 * 54 + 8];
    __shared__ __align__(16) float y50[50 * 52];
    __shared__ __align__(16) float y48[48 * 48];
    __shared__ __align__(16) float xs24[24 * 24 + 8];
    __shared__ __align__(16) float y22[22 * 24];
    __shared__ __align__(16) float y20[20 * 20];
    __shared__ __align__(16) float xs10[100];
    __shared__ float y8[64], h[64];
    __shared__ float logits[1000];
    __shared__ float red[4][2];
    __shared__ float stat[2];

    const int b = blockIdx.x, t = threadIdx.x;

    // ---- stats of layer-1 map from stripe partials (wave 0, one barrier) ----
    {
        float s = 0.f, q = 0.f;
        if (t < NS) {
            const float2 p = *(const float2*)(partial + ((size_t)b * NS + t) * 2);
            s = p.x; q = p.y;
        }
        if (t < 64) {
            #pragma unroll
            for (int off = 32; off > 0; off >>= 1) {
                s += __shfl_down(s, off, 64);
                q += __shfl_down(q, off, 64);
            }
            if (t == 0) {
                const float m = s / 11881.f;
                stat[0] = m;
                stat[1] = rsqrtf(q / 11881.f - m * m + kEps);
            }
        }
    }
    __syncthreads();
    const float m1 = stat[0], r1 = stat[1];

    // ---- LN1 + 2x2 pool -> xs54 ----
    const float* yb = y1 + (size_t)b * 109 * 112;
    #pragma unroll
    for (int it = 0; it < 12; ++it) {
        const int idx = t + it * 256;
        if (idx < 54 * 54) {
            const int ph = idx / 54, pw = idx - ph * 54;
            const int r0 = 2 * ph, c0 = 2 * pw;
            const float2 u0 = *(const float2*)(yb + r0 * 112 + c0);
            const float2 u1 = *(const float2*)(yb + (r0 + 1) * 112 + c0);
            const int i00 = r0 * 109 + c0, i10 = i00 + 109;
            const float v0 = (u0.x - m1) * r1 * g1[i00]     + be1[i00];
            const float v1 = (u0.y - m1) * r1 * g1[i00 + 1] + be1[i00 + 1];
            const float v2 = (u1.x - m1) * r1 * g1[i10]     + be1[i10];
            const float v3 = (u1.y - m1) * r1 * g1[i10 + 1] + be1[i10 + 1];
            xs54[ph * 54 + pw] = fmaxf(fmaxf(v0, v1), fmaxf(v2, v3));
        }
    }
    __syncthreads();

    // ---- L2: 54 -> conv5 -> relu -> y50 ----
    float ls = 0.f, lq = 0.f;
    #pragma unroll
    for (int it = 0; it < 3; ++it) {
        const int task = t + it * 256;
        if (task < 650) {
            const int oh = task / 13, qc = task - oh * 13;
            const int ow0 = qc * 4;
            float acc[4];
            #pragma unroll
            for (int o = 0; o < 4; ++o) acc[o] = (ow0 + o < 50) ? b2[oh * 50 + ow0 + o] : 0.f;
            #pragma unroll
            for (int kh = 0; kh < 5; ++kh) {
                const float* xp = xs54 + (oh + kh) * 54 + ow0;
                float a[8];
                #pragma unroll
                for (int i = 0; i < 4; ++i) {
                    const float2 v = *(const float2*)(xp + 2 * i);
                    a[2 * i] = v.x; a[2 * i + 1] = v.y;
                }
                #pragma unroll
                for (int kw = 0; kw < 5; ++kw) {
                    const float4 w4 = *(const float4*)(w2t + ((size_t)(kh * 5 + kw) * 50 + oh) * 52 + ow0);
                    acc[0] = fmaf(a[kw    ], w4.x, acc[0]);
                    acc[1] = fmaf(a[kw + 1], w4.y, acc[1]);
                    acc[2] = fmaf(a[kw + 2], w4.z, acc[2]);
                    acc[3] = fmaf(a[kw + 3], w4.w, acc[3]);
                }
            }
            #pragma unroll
            for (int o = 0; o < 4; ++o) {
                const float v = fmaxf(acc[o], 0.f);
                y50[oh * 52 + ow0 + o] = v;
                if (ow0 + o < 50) { ls += v; lq = fmaf(v, v, lq); }
            }
        }
    }
    const float2 s2 = block_stats4(ls, lq, 1.f / 2500.f, red, t);

    // ---- LN2 in place ----
    #pragma unroll
    for (int it = 0; it < 10; ++it) {
        const int idx = t + it * 256;
        if (idx < 2500) {
            const int oh = idx / 50, ow = idx - oh * 50;
            const int p = oh * 52 + ow;
            y50[p] = (y50[p] - s2.x) * s2.y * g2[idx] + be2[idx];
        }
    }
    __syncthreads();

    // ---- L3: 50 -> conv3 -> relu -> y48 ----
    ls = 0.f; lq = 0.f;
    #pragma unroll
    for (int it = 0; it < 3; ++it) {
        const int task = t + it * 256;
        if (task < 576) {
            const int oh = task / 12, qc = task - oh * 12;
            const int ow0 = qc * 4;
            float acc[4];
            #pragma unroll
            for (int o = 0; o < 4; ++o) acc[o] = b3[oh * 48 + ow0 + o];
            #pragma unroll
            for (int kh = 0; kh < 3; ++kh) {
                const float* xp = y50 + (oh + kh) * 52 + ow0;
                float a[6];
                #pragma unroll
                for (int i = 0; i < 3; ++i) {
                    const float2 v = *(const float2*)(xp + 2 * i);
                    a[2 * i] = v.x; a[2 * i + 1] = v.y;
                }
                #pragma unroll
                for (int kw = 0; kw < 3; ++kw) {
                    const float4 w4 = *(const float4*)(w3t + (size_t)(kh * 3 + kw) * 2304 + oh * 48 + ow0);
                    acc[0] = fmaf(a[kw    ], w4.x, acc[0]);
                    acc[1] = fmaf(a[kw + 1], w4.y, acc[1]);
                    acc[2] = fmaf(a[kw + 2], w4.z, acc[2]);
                    acc[3] = fmaf(a[kw + 3], w4.w, acc[3]);
                }
            }
            float4 st;
            #pragma unroll
            for (int o = 0; o < 4; ++o) {
                const float v = fmaxf(acc[o], 0.f);
                (&st.x)[o] = v; ls += v; lq = fmaf(v, v, lq);
            }
            *(float4*)(y48 + oh * 48 + ow0) = st;
        }
    }
    const float2 s3 = block_stats4(ls, lq, 1.f / 2304.f, red, t);

    // ---- LN3 + pool -> xs24 ----
    #pragma unroll
    for (int it = 0; it < 3; ++it) {
        const int idx = t + it * 256;
        if (idx < 576) {
            const int ph = idx / 24, pw = idx - ph * 24;
            const int r0 = 2 * ph, c0 = 2 * pw;
            const float2 u0 = *(const float2*)(y48 + r0 * 48 + c0);
            const float2 u1 = *(const float2*)(y48 + (r0 + 1) * 48 + c0);
            const int i00 = r0 * 48 + c0, i10 = i00 + 48;
            const float v0 = (u0.x - s3.x) * s3.y * g3[i00]     + be3[i00];
            const float v1 = (u0.y - s3.x) * s3.y * g3[i00 + 1] + be3[i00 + 1];
            const float v2 = (u1.x - s3.x) * s3.y * g3[i10]     + be3[i10];
            const float v3 = (u1.y - s3.x) * s3.y * g3[i10 + 1] + be3[i10 + 1];
            xs24[ph * 24 + pw] = fmaxf(fmaxf(v0, v1), fmaxf(v2, v3));
        }
    }
    __syncthreads();

    // ---- L4: 24 -> conv3 -> relu -> y22 ----
    ls = 0.f; lq = 0.f;
    if (t < 132) {
        const int oh = t / 6, qc = t - oh * 6;
        const int ow0 = qc * 4;
        float acc[4];
        #pragma unroll
        for (int o = 0; o < 4; ++o) acc[o] = (ow0 + o < 22) ? b4[oh * 22 + ow0 + o] : 0.f;
        #pragma unroll
        for (int kh = 0; kh < 3; ++kh) {
            const float* xp = xs24 + (oh + kh) * 24 + ow0;
            float a[6];
            #pragma unroll
            for (int i = 0; i < 3; ++i) {
                const float2 v = *(const float2*)(xp + 2 * i);
                a[2 * i] = v.x; a[2 * i + 1] = v.y;
            }
            #pragma unroll
            for (int kw = 0; kw < 3; ++kw) {
                const float4 w4 = *(const float4*)(w4t + ((size_t)(kh * 3 + kw) * 22 + oh) * 24 + ow0);
                acc[0] = fmaf(a[kw    ], w4.x, acc[0]);
                acc[1] = fmaf(a[kw + 1], w4.y, acc[1]);
                acc[2] = fmaf(a[kw + 2], w4.z, acc[2]);
                acc[3] = fmaf(a[kw + 3], w4.w, acc[3]);
            }
        }
        #pragma unroll
        for (int o = 0; o < 4; ++o) {
            const float v = fmaxf(acc[o], 0.f);
            y22[oh * 24 + ow0 + o] = v;
            if (ow0 + o < 22) { ls += v; lq = fmaf(v, v, lq); }
        }
    }
    const float2 s4 = block_stats4(ls, lq, 1.f / 484.f, red, t);

    // ---- LN4 in place ----
    #pragma unroll
    for (int it = 0; it < 2; ++it) {
        const int idx = t + it * 256;
        if (idx < 484) {
            const int oh = idx / 22, ow = idx - oh * 22;
            const int p = oh * 24 + ow;
            y22[p] = (y22[p] - s4.x) * s4.y * g4[idx] + be4[idx];
        }
    }
    __syncthreads();

    // ---- L5: 22 -> conv3 -> relu -> y20 ----
    ls = 0.f; lq = 0.f;
    if (t < 100) {
        const int oh = t / 5, qc = t - oh * 5;
        const int ow0 = qc * 4;
        float acc[4];
        #pragma unroll
        for (int o = 0; o < 4; ++o) acc[o] = b5[oh * 20 + ow0 + o];
        #pragma unroll
        for (int kh = 0; kh < 3; ++kh) {
            const float* xp = y22 + (oh + kh) * 24 + ow0;
            float a[6];
            #pragma unroll
            for (int i = 0; i < 3; ++i) {
                const float2 v = *(const float2*)(xp + 2 * i);
                a[2 * i] = v.x; a[2 * i + 1] = v.y;
            }
            #pragma unroll
            for (int kw = 0; kw < 3; ++kw) {
                const float4 w4 = *(const float4*)(w5t + (size_t)(kh * 3 + kw) * 400 + oh * 20 + ow0);
                acc[0] = fmaf(a[kw    ], w4.x, acc[0]);
                acc[1] = fmaf(a[kw + 1], w4.y, acc[1]);
                acc[2] = fmaf(a[kw + 2], w4.z, acc[2]);
                acc[3] = fmaf(a[kw + 3], w4.w, acc[3]);
            }
        }
        #pragma unroll
        for (int o = 0; o < 4; ++o) {
            const float v = fmaxf(acc[o], 0.f);
            y20[oh * 20 + ow0 + o] = v;
            ls += v; lq = fmaf(v, v, lq);
        }
    }
    const float2 s5 = block_stats4(ls, lq, 1.f / 400.f, red, t);

    // ---- LN5 + pool -> xs10 ----
    if (t < 100) {
        const int ph = t / 10, pw = t - ph * 10;
        const int r0 = 2 * ph, c0 = 2 * pw;
        const float2 u0 = *(const float2*)(y20 + r0 * 20 + c0);
        const float2 u1 = *(const float2*)(y20 + (r0 + 1) * 20 + c0);
        const int i00 = r0 * 20 + c0, i10 = i00 + 20;
        const float v0 = (u0.x - s5.x) * s5.y * g5[i00]     + be5[i00];
        const float v1 = (u0.y - s5.x) * s5.y * g5[i00 + 1] + be5[i00 + 1];
        const float v2 = (u1.x - s5.x) * s5.y * g5[i10]     + be5[i10];
        const float v3 = (u1.y - s5.x) * s5.y * g5[i10 + 1] + be5[i10 + 1];
        xs10[ph * 10 + pw] = fmaxf(fmaxf(v0, v1), fmaxf(v2, v3));
    }
    __syncthreads();

    // ---- L6: 10 -> conv3 -> relu -> y8 ----
    ls = 0.f; lq = 0.f;
    if (t < 16) {
        const int oh = t / 2, qc = t - oh * 2;
        const int ow0 = qc * 4;
        float acc[4];
        #pragma unroll
        for (int o = 0; o < 4; ++o) acc[o] = b6[oh * 8 + ow0 + o];
        #pragma unroll
        for (int kh = 0; kh < 3; ++kh) {
            const float* xp = xs10 + (oh + kh) * 10 + ow0;
            float a[6];
            #pragma unroll
            for (int i = 0; i < 3; ++i) {
                const float2 v = *(const float2*)(xp + 2 * i);
                a[2 * i] = v.x; a[2 * i + 1] = v.y;
            }
            #pragma unroll
            for (int kw = 0; kw < 3; ++kw) {
                const float4 w4 = *(const float4*)(w6t + (size_t)(kh * 3 + kw) * 64 + oh * 8 + ow0);
                acc[0] = fmaf(a[kw    ], w4.x, acc[0]);
                acc[1] = fmaf(a[kw + 1], w4.y, acc[1]);
                acc[2] = fmaf(a[kw + 2], w4.z, acc[2]);
                acc[3] = fmaf(a[kw + 3], w4.w, acc[3]);
            }
        }
        #pragma unroll
        for (int o = 0; o < 4; ++o) {
            const float v = fmaxf(acc[o], 0.f);
            y8[oh * 8 + ow0 + o] = v;
            ls += v; lq = fmaf(v, v, lq);
        }
    }
    const float2 s6 = block_stats4(ls, lq, 1.f / 64.f, red, t);

    // ---- LN6 -> h ----
    if (t < 64) h[t] = (y8[t] - s6.x) * s6.y * g6[t] + be6[t];
    __syncthreads();

    // ---- FC 64 -> 1000 ----
    #pragma unroll
    for (int it = 0; it < 4; ++it) {
        const int j = t + it * 256;
        if (j < 1000) {
            const float4* wr = (const float4*)(fcw + (size_t)j * 64);
            float acc = fcb[j];
            #pragma unroll
            for (int k = 0; k < 16; ++k) {
                const float4 w4 = wr[k];
                acc = fmaf(h[4 * k], w4.x,
                      fmaf(h[4 * k + 1], w4.y,
                      fmaf(h[4 * k + 2], w4.z,
                      fmaf(h[4 * k + 3], w4.w, acc))));
            }
            logits[j] = acc;
        }
    }
    __syncthreads();

    // ---- softmax ----
    float lmax = -INFINITY;
    #pragma unroll
    for (int it = 0; it < 4; ++it) {
        const int j = t + it * 256;
        if (j < 1000) lmax = fmaxf(lmax, logits[j]);
    }
    #pragma unroll
    for (int off = 32; off > 0; off >>= 1) lmax = fmaxf(lmax, __shfl_down(lmax, off, 64));
    if ((t & 63) == 0) red[t >> 6][0] = lmax;
    __syncthreads();
    const float gmax = fmaxf(fmaxf(red[0][0], red[1][0]), fmaxf(red[2][0], red[3][0]));
    __syncthreads();
    float lsum = 0.f;
    #pragma unroll
    for (int it = 0; it < 4; ++it) {
        const int j = t + it * 256;
        if (j < 1000) {
            const float e = __expf(logits[j] - gmax);
            logits[j] = e;
            lsum += e;
        }
    }
    #pragma unroll
    for (int off = 32; off > 0; off >>= 1) lsum += __shfl_down(lsum, off, 64);
    if ((t & 63) == 0) red[t >> 6][0] = lsum;
    __syncthreads();
    const float inv = 1.f / (red[0][0] + red[1][0] + red[2][0] + red[3][0]);
    #pragma unroll
    for (int it = 0; it < 4; ++it) {
        const int j = t + it * 256;
        if (j < 1000) out[(size_t)b * 1000 + j] = logits[j] * inv;
    }
}

extern "C" void kernel_launch(void* const* d_in, const int* in_sizes, int n_in,
                              void* d_out, int out_size, void* d_ws, size_t ws_size,
                              hipStream_t stream) {
    const float* x   = (const float*)d_in[0];
    const float* w1  = (const float*)d_in[1];
    const float* b1  = (const float*)d_in[2];
    const float* g1  = (const float*)d_in[3];
    const float* be1 = (const float*)d_in[4];
    const float* w2  = (const float*)d_in[5];
    const float* b2  = (const float*)d_in[6];
    const float* g2  = (const float*)d_in[7];
    const float* be2 = (const float*)d_in[8];
    const float* w3  = (const float*)d_in[9];
    const float* b3  = (const float*)d_in[10];
    const float* g3  = (const float*)d_in[11];
    const float* be3 = (const float*)d_in[12];
    const float* w4  = (const float*)d_in[13];
    const float* b4  = (const float*)d_in[14];
    const float* g4  = (const float*)d_in[15];
    const float* be4 = (const float*)d_in[16];
    const float* w5  = (const float*)d_in[17];
    const float* b5  = (const float*)d_in[18];
    const float* g5  = (const float*)d_in[19];
    const float* be5 = (const float*)d_in[20];
    const float* w6  = (const float*)d_in[21];
    const float* b6  = (const float*)d_in[22];
    const float* g6  = (const float*)d_in[23];
    const float* be6 = (const float*)d_in[24];
    const float* fcw = (const float*)d_in[25];
    const float* fcb = (const float*)d_in[26];

    float* y1p  = (float*)d_ws;                 // 128*109*112 = 1,562,624
    float* w1t  = y1p  + 1562624;               // 49*109*112  =   598,192
    float* w2t  = w1t  + 598192;                // 25*50*52    =    65,000
    float* w3t  = w2t  + 65000;                 // 9*2304      =    20,736
    float* w4t  = w3t  + 20736;                 // 9*22*24     =     4,752
    float* w5t  = w4t  + 4752;                  // 9*400       =     3,600
    float* w6t  = w5t  + 3600;                  // 9*64        =       576
    float* part = w6t  + 576;                   // 128*28*2    =     7,168

    transpose_weights<<<512, 256, 0, stream>>>(w1, w2, w3, w4, w5, w6,
                                               w1t, w2t, w3t, w4t, w5t, w6t);

    conv1<<<dim3(28, 64), 128, 0, stream>>>(x, w1t, b1, y1p, part);

    tail<<<128, 256, 0, stream>>>(y1p, part, g1, be1,
                                  w2t, b2, g2, be2,
                                  w3t, b3, g3, be3,
                                  w4t, b4, g4, be4,
                                  w5t, b5, g5, be5,
                                  w6t, b6, g6, be6,
                                  fcw, fcb, (float*)d_out);
}

// Round 5
// 53.058 us; speedup vs baseline: 2.0954x; 1.0303x over previous
//
#include <hip/hip_runtime.h>
#include <math.h>

static constexpr float kEps = 1e-5f;

// ---------- kernel 1: transpose w1 only -> w1t [49][109][112] (pads = 0) ----------
__global__ __launch_bounds__(256)
void transpose_w1(const float* __restrict__ w1, float* __restrict__ t1)
{
    const int tid = blockIdx.x * blockDim.x + threadIdx.x;
    const int nt  = gridDim.x * blockDim.x;
    for (int i = tid; i < 49 * 109 * 112; i += nt) {
        const int kk = i / (109 * 112), r = i % (109 * 112);
        const int oh = r / 112, ow = r % 112;
        t1[i] = (ow < 109) ? w1[(oh * 109 + ow) * 49 + kk] : 0.f;
    }
}

// ---------- kernel 2: conv1 (+ small transposes in extra blocks) ----------
// L1: 224 -> conv(7,s2) -> relu -> y[128][109][112] + partial LN sums.
// blockIdx.y == 64 blocks instead transpose w2..w6 and pack g1p/be1p.
__global__ __launch_bounds__(128)
void conv1(const float* __restrict__ x, const float* __restrict__ wt,
           const float* __restrict__ bias, float* __restrict__ y,
           float* __restrict__ partial,
           const float* __restrict__ w2, const float* __restrict__ w3,
           const float* __restrict__ w4, const float* __restrict__ w5,
           const float* __restrict__ w6,
           const float* __restrict__ g1, const float* __restrict__ be1,
           float* __restrict__ w2t, float* __restrict__ w3t,
           float* __restrict__ w4t, float* __restrict__ w5t,
           float* __restrict__ w6t,
           float4* __restrict__ g1p, float4* __restrict__ be1p)
{
    constexpr int IN = 224, OUT = 109, K = 7, RPS = 4, QPR = 28, NS = 28;
    constexpr int ROWS = (RPS - 1) * 2 + K;   // 13
    __shared__ __align__(16) float xs0[ROWS * IN];
    __shared__ __align__(16) float xs1[ROWS * IN];
    __shared__ float red[2][4];

    const int s = blockIdx.x, bp = blockIdx.y, t = threadIdx.x;

    if (bp == 64) {
        // ---- side work: small weight transposes + LN1-pool param packing ----
        const int tid = s * 128 + t;
        const int nt  = 28 * 128;
        for (int i = tid; i < 25 * 50 * 52; i += nt) {          // w2t [25][50][52]
            const int kk = i / (50 * 52), r = i % (50 * 52);
            const int oh = r / 52, ow = r % 52;
            w2t[i] = (ow < 50) ? w2[(oh * 50 + ow) * 25 + kk] : 0.f;
        }
        for (int i = tid; i < 9 * 2304; i += nt) {              // w3t [9][2304]
            const int kk = i / 2304, idx = i % 2304;
            w3t[i] = w3[idx * 9 + kk];
        }
        for (int i = tid; i < 9 * 22 * 24; i += nt) {           // w4t [9][22][24]
            const int kk = i / (22 * 24), r = i % (22 * 24);
            const int oh = r / 24, ow = r % 24;
            w4t[i] = (ow < 22) ? w4[(oh * 22 + ow) * 9 + kk] : 0.f;
        }
        for (int i = tid; i < 9 * 400; i += nt) {               // w5t [9][400]
            const int kk = i / 400, idx = i % 400;
            w5t[i] = w5[idx * 9 + kk];
        }
        for (int i = tid; i < 9 * 64; i += nt) {                // w6t [9][64]
            const int kk = i / 64, idx = i % 64;
            w6t[i] = w6[idx * 9 + kk];
        }
        for (int i = tid; i < 54 * 54; i += nt) {               // pool-window params
            const int ph = i / 54, pw = i - ph * 54;
            const int i00 = (2 * ph) * 109 + 2 * pw, i10 = i00 + 109;
            g1p[i]  = make_float4(g1[i00],  g1[i00 + 1],  g1[i10],  g1[i10 + 1]);
            be1p[i] = make_float4(be1[i00], be1[i00 + 1], be1[i10], be1[i10 + 1]);
        }
        return;
    }

    const int b0 = 2 * bp, b1 = b0 + 1;
    const int oh0 = s * RPS, ih0 = oh0 * 2;
    const int nrows = min(ROWS, IN - ih0);
    {
        const float4* g0 = (const float4*)(x + ((size_t)b0 * IN + ih0) * IN);
        const float4* g1r = (const float4*)(x + ((size_t)b1 * IN + ih0) * IN);
        float4* s0 = (float4*)xs0;
        float4* s1 = (float4*)xs1;
        const int n4 = nrows * (IN / 4);
        for (int i = t; i < n4; i += 128) { s0[i] = g0[i]; s1[i] = g1r[i]; }
    }
    __syncthreads();

    float lsum0 = 0.f, lsq0 = 0.f, lsum1 = 0.f, lsq1 = 0.f;
    if (t < RPS * QPR) {
        const int r = t / QPR, qc = t - r * QPR;
        const int oh = oh0 + r, ow0 = qc * 4;
        if (oh < OUT) {
            float acc0[4], acc1[4];
            #pragma unroll
            for (int o = 0; o < 4; ++o) {
                const float bv = (ow0 + o < OUT) ? bias[oh * OUT + ow0 + o] : 0.f;
                acc0[o] = bv; acc1[o] = bv;
            }
            const int lr0 = r * 2, c0 = ow0 * 2;
            #pragma unroll
            for (int kh = 0; kh < K; ++kh) {
                const float* p0 = xs0 + (lr0 + kh) * IN + c0;
                const float* p1 = xs1 + (lr0 + kh) * IN + c0;
                float a0[14], a1[14];
                #pragma unroll
                for (int i = 0; i < 7; ++i) {
                    const float2 v0 = *(const float2*)(p0 + 2 * i);
                    const float2 v1 = *(const float2*)(p1 + 2 * i);
                    a0[2 * i] = v0.x; a0[2 * i + 1] = v0.y;
                    a1[2 * i] = v1.x; a1[2 * i + 1] = v1.y;
                }
                #pragma unroll
                for (int kw = 0; kw < K; ++kw) {
                    const float4 w4 = *(const float4*)(wt + ((size_t)(kh * 7 + kw) * OUT + oh) * 112 + ow0);
                    acc0[0] = fmaf(a0[kw    ], w4.x, acc0[0]);  acc1[0] = fmaf(a1[kw    ], w4.x, acc1[0]);
                    acc0[1] = fmaf(a0[kw + 2], w4.y, acc0[1]);  acc1[1] = fmaf(a1[kw + 2], w4.y, acc1[1]);
                    acc0[2] = fmaf(a0[kw + 4], w4.z, acc0[2]);  acc1[2] = fmaf(a1[kw + 4], w4.z, acc1[2]);
                    acc0[3] = fmaf(a0[kw + 6], w4.w, acc0[3]);  acc1[3] = fmaf(a1[kw + 6], w4.w, acc1[3]);
                }
            }
            float4 st0, st1;
            #pragma unroll
            for (int o = 0; o < 4; ++o) {
                const float v0 = fmaxf(acc0[o], 0.f), v1 = fmaxf(acc1[o], 0.f);
                if (ow0 + o < OUT) {
                    lsum0 += v0; lsq0 = fmaf(v0, v0, lsq0);
                    lsum1 += v1; lsq1 = fmaf(v1, v1, lsq1);
                }
                (&st0.x)[o] = v0; (&st1.x)[o] = v1;
            }
            *(float4*)(y + ((size_t)b0 * OUT + oh) * 112 + ow0) = st0;
            *(float4*)(y + ((size_t)b1 * OUT + oh) * 112 + ow0) = st1;
        }
    }
    #pragma unroll
    for (int off = 32; off > 0; off >>= 1) {
        lsum0 += __shfl_down(lsum0, off, 64);  lsq0 += __shfl_down(lsq0, off, 64);
        lsum1 += __shfl_down(lsum1, off, 64);  lsq1 += __shfl_down(lsq1, off, 64);
    }
    if ((t & 63) == 0) {
        const int w = t >> 6;
        red[w][0] = lsum0; red[w][1] = lsq0; red[w][2] = lsum1; red[w][3] = lsq1;
    }
    __syncthreads();
    if (t == 0) {
        const float a = red[0][0] + red[1][0], bq = red[0][1] + red[1][1];
        const float c = red[0][2] + red[1][2], d  = red[0][3] + red[1][3];
        partial[((size_t)b0 * NS + s) * 2]     = a;
        partial[((size_t)b0 * NS + s) * 2 + 1] = bq;
        partial[((size_t)b1 * NS + s) * 2]     = c;
        partial[((size_t)b1 * NS + s) * 2 + 1] = d;
    }
}

// ---------- block stats for 16 waves: one barrier, all threads get result ----------
__device__ inline float2 bstats(float ls, float lq, float invN, float (*red)[2], int t)
{
    #pragma unroll
    for (int off = 32; off > 0; off >>= 1) {
        ls += __shfl_down(ls, off, 64);
        lq += __shfl_down(lq, off, 64);
    }
    if ((t & 63) == 0) { red[t >> 6][0] = ls; red[t >> 6][1] = lq; }
    __syncthreads();
    float s = 0.f, q = 0.f;
    #pragma unroll
    for (int w = 0; w < 16; ++w) { s += red[w][0]; q += red[w][1]; }
    const float m = s * invN;
    return make_float2(m, rsqrtf(q * invN - m * m + kEps));
}

// ---------- kernel 3: everything after conv1, one 1024-thread block per sample ----------
__global__ __launch_bounds__(1024)
void tail(const float* __restrict__ y1, const float* __restrict__ partial,
          const float4* __restrict__ g1p, const float4* __restrict__ be1p,
          const float* __restrict__ w2t, const float* __restrict__ b2,
          const float* __restrict__ g2, const float* __restrict__ be2,
          const float* __restrict__ w3t, const float* __restrict__ b3,
          const float* __restrict__ g3, const float* __restrict__ be3,
          const float* __restrict__ w4t, const float* __restrict__ b4,
          const float* __restrict__ g4, const float* __restrict__ be4,
          const float* __restrict__ w5t, const float* __restrict__ b5,
          const float* __restrict__ g5, const float* __restrict__ be5,
          const float* __restrict__ w6t, const float* __restrict__ b6,
          const float* __restrict__ g6, const float* __restrict__ be6,
          const float* __restrict__ fcw, const float* __restrict__ fcb,
          float* __restrict__ out)
{
    __shared__ __align__(16) float xs54[54 * 54 + 8];
    __shared__ __align__(16) float y50[50 * 52];
    __shared__ __align__(16) float y48[48 * 48];
    __shared__ __align__(16) float xs24[24 * 24 + 8];
    __shared__ __align__(16) float y22[22 * 24];
    __shared__ __align__(16) float y20[20 * 20];
    __shared__ __align__(16) float xs10[100];
    __shared__ float y8[64], h[64];
    __shared__ float red[16][2];

    const int b = blockIdx.x, t = threadIdx.x;
    const int lane = t & 63;

    // ---- LN1 stats from the 28 stripe partials: per-wave, barrier-free ----
    float s = 0.f, q = 0.f;
    if (lane < 28) {
        const float2 p = *(const float2*)(partial + ((size_t)b * 28 + lane) * 2);
        s = p.x; q = p.y;
    }
    #pragma unroll
    for (int off = 32; off > 0; off >>= 1) {
        s += __shfl_down(s, off, 64);
        q += __shfl_down(q, off, 64);
    }
    s = __shfl(s, 0, 64); q = __shfl(q, 0, 64);
    const float m1 = s / 11881.f;
    const float r1 = rsqrtf(q / 11881.f - m1 * m1 + kEps);

    // ---- LN1 + 2x2 pool -> xs54 ----
    const float* yb = y1 + (size_t)b * 109 * 112;
    #pragma unroll
    for (int it = 0; it < 3; ++it) {
        const int idx = t + it * 1024;
        if (idx < 54 * 54) {
            const int ph = idx / 54, pw = idx - ph * 54;
            const int r0 = 2 * ph, c0 = 2 * pw;
            const float2 u0 = *(const float2*)(yb + r0 * 112 + c0);
            const float2 u1 = *(const float2*)(yb + (r0 + 1) * 112 + c0);
            const float4 g = g1p[idx], be = be1p[idx];
            const float v0 = (u0.x - m1) * r1 * g.x + be.x;
            const float v1 = (u0.y - m1) * r1 * g.y + be.y;
            const float v2 = (u1.x - m1) * r1 * g.z + be.z;
            const float v3 = (u1.y - m1) * r1 * g.w + be.w;
            xs54[ph * 54 + pw] = fmaxf(fmaxf(v0, v1), fmaxf(v2, v3));
        }
    }
    __syncthreads();

    // ---- L2: 54 -> conv5 -> relu -> y50 (650 tasks, 1 round) ----
    float ls = 0.f, lq = 0.f;
    if (t < 650) {
        const int oh = t / 13, qc = t - oh * 13;
        const int ow0 = qc * 4;
        float acc[4];
        #pragma unroll
        for (int o = 0; o < 4; ++o) acc[o] = (ow0 + o < 50) ? b2[oh * 50 + ow0 + o] : 0.f;
        #pragma unroll
        for (int kh = 0; kh < 5; ++kh) {
            const float* xp = xs54 + (oh + kh) * 54 + ow0;
            float a[8];
            #pragma unroll
            for (int i = 0; i < 4; ++i) {
                const float2 v = *(const float2*)(xp + 2 * i);
                a[2 * i] = v.x; a[2 * i + 1] = v.y;
            }
            #pragma unroll
            for (int kw = 0; kw < 5; ++kw) {
                const float4 w4 = *(const float4*)(w2t + ((size_t)(kh * 5 + kw) * 50 + oh) * 52 + ow0);
                acc[0] = fmaf(a[kw    ], w4.x, acc[0]);
                acc[1] = fmaf(a[kw + 1], w4.y, acc[1]);
                acc[2] = fmaf(a[kw + 2], w4.z, acc[2]);
                acc[3] = fmaf(a[kw + 3], w4.w, acc[3]);
            }
        }
        #pragma unroll
        for (int o = 0; o < 4; ++o) {
            const float v = fmaxf(acc[o], 0.f);
            y50[oh * 52 + ow0 + o] = v;
            if (ow0 + o < 50) { ls += v; lq = fmaf(v, v, lq); }
        }
    }
    const float2 s2 = bstats(ls, lq, 1.f / 2500.f, red, t);

    // ---- LN2 in place ----
    #pragma unroll
    for (int it = 0; it < 3; ++it) {
        const int idx = t + it * 1024;
        if (idx < 2500) {
            const int oh = idx / 50, ow = idx - oh * 50;
            const int p = oh * 52 + ow;
            y50[p] = (y50[p] - s2.x) * s2.y * g2[idx] + be2[idx];
        }
    }
    __syncthreads();

    // ---- L3: 50 -> conv3 -> relu -> y48 (576 tasks, 1 round) ----
    ls = 0.f; lq = 0.f;
    if (t < 576) {
        const int oh = t / 12, qc = t - oh * 12;
        const int ow0 = qc * 4;
        float acc[4];
        #pragma unroll
        for (int o = 0; o < 4; ++o) acc[o] = b3[oh * 48 + ow0 + o];
        #pragma unroll
        for (int kh = 0; kh < 3; ++kh) {
            const float* xp = y50 + (oh + kh) * 52 + ow0;
            float a[6];
            #pragma unroll
            for (int i = 0; i < 3; ++i) {
                const float2 v = *(const float2*)(xp + 2 * i);
                a[2 * i] = v.x; a[2 * i + 1] = v.y;
            }
            #pragma unroll
            for (int kw = 0; kw < 3; ++kw) {
                const float4 w4 = *(const float4*)(w3t + (size_t)(kh * 3 + kw) * 2304 + oh * 48 + ow0);
                acc[0] = fmaf(a[kw    ], w4.x, acc[0]);
                acc[1] = fmaf(a[kw + 1], w4.y, acc[1]);
                acc[2] = fmaf(a[kw + 2], w4.z, acc[2]);
                acc[3] = fmaf(a[kw + 3], w4.w, acc[3]);
            }
        }
        float4 st;
        #pragma unroll
        for (int o = 0; o < 4; ++o) {
            const float v = fmaxf(acc[o], 0.f);
            (&st.x)[o] = v; ls += v; lq = fmaf(v, v, lq);
        }
        *(float4*)(y48 + oh * 48 + ow0) = st;
    }
    const float2 s3 = bstats(ls, lq, 1.f / 2304.f, red, t);

    // ---- LN3 + pool -> xs24 (576 tasks, 1 round) ----
    if (t < 576) {
        const int ph = t / 24, pw = t - ph * 24;
        const int r0 = 2 * ph, c0 = 2 * pw;
        const float2 u0 = *(const float2*)(y48 + r0 * 48 + c0);
        const float2 u1 = *(const float2*)(y48 + (r0 + 1) * 48 + c0);
        const int i00 = r0 * 48 + c0, i10 = i00 + 48;
        const float v0 = (u0.x - s3.x) * s3.y * g3[i00]     + be3[i00];
        const float v1 = (u0.y - s3.x) * s3.y * g3[i00 + 1] + be3[i00 + 1];
        const float v2 = (u1.x - s3.x) * s3.y * g3[i10]     + be3[i10];
        const float v3 = (u1.y - s3.x) * s3.y * g3[i10 + 1] + be3[i10 + 1];
        xs24[ph * 24 + pw] = fmaxf(fmaxf(v0, v1), fmaxf(v2, v3));
    }
    __syncthreads();

    // ---- L4: 24 -> conv3 -> relu -> y22 ----
    ls = 0.f; lq = 0.f;
    if (t < 132) {
        const int oh = t / 6, qc = t - oh * 6;
        const int ow0 = qc * 4;
        float acc[4];
        #pragma unroll
        for (int o = 0; o < 4; ++o) acc[o] = (ow0 + o < 22) ? b4[oh * 22 + ow0 + o] : 0.f;
        #pragma unroll
        for (int kh = 0; kh < 3; ++kh) {
            const float* xp = xs24 + (oh + kh) * 24 + ow0;
            float a[6];
            #pragma unroll
            for (int i = 0; i < 3; ++i) {
                const float2 v = *(const float2*)(xp + 2 * i);
                a[2 * i] = v.x; a[2 * i + 1] = v.y;
            }
            #pragma unroll
            for (int kw = 0; kw < 3; ++kw) {
                const float4 w4 = *(const float4*)(w4t + ((size_t)(kh * 3 + kw) * 22 + oh) * 24 + ow0);
                acc[0] = fmaf(a[kw    ], w4.x, acc[0]);
                acc[1] = fmaf(a[kw + 1], w4.y, acc[1]);
                acc[2] = fmaf(a[kw + 2], w4.z, acc[2]);
                acc[3] = fmaf(a[kw + 3], w4.w, acc[3]);
            }
        }
        #pragma unroll
        for (int o = 0; o < 4; ++o) {
            const float v = fmaxf(acc[o], 0.f);
            y22[oh * 24 + ow0 + o] = v;
            if (ow0 + o < 22) { ls += v; lq = fmaf(v, v, lq); }
        }
    }
    const float2 s4 = bstats(ls, lq, 1.f / 484.f, red, t);

    // ---- LN4 in place ----
    if (t < 484) {
        const int oh = t / 22, ow = t - oh * 22;
        const int p = oh * 24 + ow;
        y22[p] = (y22[p] - s4.x) * s4.y * g4[t] + be4[t];
    }
    __syncthreads();

    // ---- L5: 22 -> conv3 -> relu -> y20 ----
    ls = 0.f; lq = 0.f;
    if (t < 100) {
        const int oh = t / 5, qc = t - oh * 5;
        const int ow0 = qc * 4;
        float acc[4];
        #pragma unroll
        for (int o = 0; o < 4; ++o) acc[o] = b5[oh * 20 + ow0 + o];
        #pragma unroll
        for (int kh = 0; kh < 3; ++kh) {
            const float* xp = y22 + (oh + kh) * 24 + ow0;
            float a[6];
            #pragma unroll
            for (int i = 0; i < 3; ++i) {
                const float2 v = *(const float2*)(xp + 2 * i);
                a[2 * i] = v.x; a[2 * i + 1] = v.y;
            }
            #pragma unroll
            for (int kw = 0; kw < 3; ++kw) {
                const float4 w4 = *(const float4*)(w5t + (size_t)(kh * 3 + kw) * 400 + oh * 20 + ow0);
                acc[0] = fmaf(a[kw    ], w4.x, acc[0]);
                acc[1] = fmaf(a[kw + 1], w4.y, acc[1]);
                acc[2] = fmaf(a[kw + 2], w4.z, acc[2]);
                acc[3] = fmaf(a[kw + 3], w4.w, acc[3]);
            }
        }
        #pragma unroll
        for (int o = 0; o < 4; ++o) {
            const float v = fmaxf(acc[o], 0.f);
            y20[oh * 20 + ow0 + o] = v;
            ls += v; lq = fmaf(v, v, lq);
        }
    }
    const float2 s5 = bstats(ls, lq, 1.f / 400.f, red, t);

    // ---- LN5 + pool -> xs10 ----
    if (t < 100) {
        const int ph = t / 10, pw = t - ph * 10;
        const int r0 = 2 * ph, c0 = 2 * pw;
        const float2 u0 = *(const float2*)(y20 + r0 * 20 + c0);
        const float2 u1 = *(const float2*)(y20 + (r0 + 1) * 20 + c0);
        const int i00 = r0 * 20 + c0, i10 = i00 + 20;
        const float v0 = (u0.x - s5.x) * s5.y * g5[i00]     + be5[i00];
        const float v1 = (u0.y - s5.x) * s5.y * g5[i00 + 1] + be5[i00 + 1];
        const float v2 = (u1.x - s5.x) * s5.y * g5[i10]     + be5[i10];
        const float v3 = (u1.y - s5.x) * s5.y * g5[i10 + 1] + be5[i10 + 1];
        xs10[ph * 10 + pw] = fmaxf(fmaxf(v0, v1), fmaxf(v2, v3));
    }
    __syncthreads();

    // ---- L6: 10 -> conv3 -> relu -> y8 ----
    ls = 0.f; lq = 0.f;
    if (t < 16) {
        const int oh = t / 2, qc = t - oh * 2;
        const int ow0 = qc * 4;
        float acc[4];
        #pragma unroll
        for (int o = 0; o < 4; ++o) acc[o] = b6[oh * 8 + ow0 + o];
        #pragma unroll
        for (int kh = 0; kh < 3; ++kh) {
            const float* xp = xs10 + (oh + kh) * 10 + ow0;
            float a[6];
            #pragma unroll
            for (int i = 0; i < 3; ++i) {
                const float2 v = *(const float2*)(xp + 2 * i);
                a[2 * i] = v.x; a[2 * i + 1] = v.y;
            }
            #pragma unroll
            for (int kw = 0; kw < 3; ++kw) {
                const float4 w4 = *(const float4*)(w6t + (size_t)(kh * 3 + kw) * 64 + oh * 8 + ow0);
                acc[0] = fmaf(a[kw    ], w4.x, acc[0]);
                acc[1] = fmaf(a[kw + 1], w4.y, acc[1]);
                acc[2] = fmaf(a[kw + 2], w4.z, acc[2]);
                acc[3] = fmaf(a[kw + 3], w4.w, acc[3]);
            }
        }
        #pragma unroll
        for (int o = 0; o < 4; ++o) {
            const float v = fmaxf(acc[o], 0.f);
            y8[oh * 8 + ow0 + o] = v;
            ls += v; lq = fmaf(v, v, lq);
        }
    }
    const float2 s6 = bstats(ls, lq, 1.f / 64.f, red, t);

    // ---- LN6 -> h ----
    if (t < 64) h[t] = (y8[t] - s6.x) * s6.y * g6[t] + be6[t];
    __syncthreads();

    // ---- FC 64 -> 1000 (1 task/thread, logit in register) + softmax ----
    float lj = -INFINITY;
    if (t < 1000) {
        const float4* wr = (const float4*)(fcw + (size_t)t * 64);
        float acc = fcb[t];
        #pragma unroll
        for (int k = 0; k < 16; ++k) {
            const float4 w4 = wr[k];
            acc = fmaf(h[4 * k], w4.x,
                  fmaf(h[4 * k + 1], w4.y,
                  fmaf(h[4 * k + 2], w4.z,
                  fmaf(h[4 * k + 3], w4.w, acc))));
        }
        lj = acc;
    }
    float mx = lj;
    #pragma unroll
    for (int off = 32; off > 0; off >>= 1) mx = fmaxf(mx, __shfl_down(mx, off, 64));
    if (lane == 0) red[t >> 6][0] = mx;
    __syncthreads();
    float gmax = red[0][0];
    #pragma unroll
    for (int w = 1; w < 16; ++w) gmax = fmaxf(gmax, red[w][0]);

    const float e = (t < 1000) ? __expf(lj - gmax) : 0.f;
    float ssum = e;
    #pragma unroll
    for (int off = 32; off > 0; off >>= 1) ssum += __shfl_down(ssum, off, 64);
    if (lane == 0) red[t >> 6][1] = ssum;
    __syncthreads();
    float tot = 0.f;
    #pragma unroll
    for (int w = 0; w < 16; ++w) tot += red[w][1];
    if (t < 1000) out[(size_t)b * 1000 + t] = e / tot;
}

extern "C" void kernel_launch(void* const* d_in, const int* in_sizes, int n_in,
                              void* d_out, int out_size, void* d_ws, size_t ws_size,
                              hipStream_t stream) {
    const float* x   = (const float*)d_in[0];
    const float* w1  = (const float*)d_in[1];
    const float* b1  = (const float*)d_in[2];
    const float* g1  = (const float*)d_in[3];
    const float* be1 = (const float*)d_in[4];
    const float* w2  = (const float*)d_in[5];
    const float* b2  = (const float*)d_in[6];
    const float* g2  = (const float*)d_in[7];
    const float* be2 = (const float*)d_in[8];
    const float* w3  = (const float*)d_in[9];
    const float* b3  = (const float*)d_in[10];
    const float* g3  = (const float*)d_in[11];
    const float* be3 = (const float*)d_in[12];
    const float* w4  = (const float*)d_in[13];
    const float* b4  = (const float*)d_in[14];
    const float* g4  = (const float*)d_in[15];
    const float* be4 = (const float*)d_in[16];
    const float* w5  = (const float*)d_in[17];
    const float* b5  = (const float*)d_in[18];
    const float* g5  = (const float*)d_in[19];
    const float* be5 = (const float*)d_in[20];
    const float* w6  = (const float*)d_in[21];
    const float* b6  = (const float*)d_in[22];
    const float* g6  = (const float*)d_in[23];
    const float* be6 = (const float*)d_in[24];
    const float* fcw = (const float*)d_in[25];
    const float* fcb = (const float*)d_in[26];

    float* y1p  = (float*)d_ws;                 // 128*109*112 = 1,562,624
    float* w1t  = y1p  + 1562624;               // 49*109*112  =   598,192
    float* w2t  = w1t  + 598192;                // 25*50*52    =    65,000
    float* w3t  = w2t  + 65000;                 // 9*2304      =    20,736
    float* w4t  = w3t  + 20736;                 // 9*22*24     =     4,752
    float* w5t  = w4t  + 4752;                  // 9*400       =     3,600
    float* w6t  = w5t  + 3600;                  // 9*64        =       576
    float* part = w6t  + 576;                   // 128*28*2    =     7,168
    float* g1pp = part + 7168;                  // 2916*4      =    11,664
    float* be1pp= g1pp + 11664;                 // 2916*4      =    11,664

    transpose_w1<<<512, 256, 0, stream>>>(w1, w1t);

    conv1<<<dim3(28, 65), 128, 0, stream>>>(x, w1t, b1, y1p, part,
                                            w2, w3, w4, w5, w6, g1, be1,
                                            w2t, w3t, w4t, w5t, w6t,
                                            (float4*)g1pp, (float4*)be1pp);

    tail<<<128, 1024, 0, stream>>>(y1p, part,
                                   (const float4*)g1pp, (const float4*)be1pp,
                                   w2t, b2, g2, be2,
                                   w3t, b3, g3, be3,
                                   w4t, b4, g4, be4,
                                   w5t, b5, g5, be5,
                                   w6t, b6, g6, be6,
                                   fcw, fcb, (float*)d_out);
}